// Round 1
// 2492.718 us; speedup vs baseline: 1.0513x; 1.0513x over previous
//
#include <hip/hip_runtime.h>
#include <hip/hip_bf16.h>

// FARGAN vocoder on MI355X. Sizes fixed by the reference:
#define SS      64
#define NSUB    4
#define LPREV   512
#define NF      193
#define NFRAMES 100
#define BATCH   64
#define RPW     16     // batch rows per workgroup (MFMA M)

typedef __attribute__((ext_vector_type(8))) short   short8;   // 8 bf16 (4 VGPRs)
typedef __attribute__((ext_vector_type(4))) float   floatx4;  // MFMA C/D

// ---------- scalar helpers ----------
__device__ __forceinline__ float bf2f(unsigned short u) {
    return __uint_as_float(((unsigned int)u) << 16);
}
__device__ __forceinline__ unsigned short f2bf(float x) {
    unsigned int u = __float_as_uint(x);
    return (unsigned short)((u + 0x7fffu + ((u >> 16) & 1u)) >> 16);
}
__device__ __forceinline__ unsigned int packbf(float a, float b) {
    return (unsigned int)f2bf(a) | ((unsigned int)f2bf(b) << 16);
}
__device__ __forceinline__ float fexp2(float x) {
#if __has_builtin(__builtin_amdgcn_exp2f)
    return __builtin_amdgcn_exp2f(x);
#else
    return exp2f(x);
#endif
}
__device__ __forceinline__ float frcp(float x) {
#if __has_builtin(__builtin_amdgcn_rcpf)
    return __builtin_amdgcn_rcpf(x);
#else
    return 1.0f / x;
#endif
}
__device__ __forceinline__ float fsig(float x) {
    return frcp(1.0f + fexp2(-1.442695041f * x));
}
__device__ __forceinline__ float ftanh(float x) {
    return fmaf(2.0f, frcp(1.0f + fexp2(-2.885390082f * x)), -1.0f);
}
__device__ __forceinline__ float ld1f(int f32, const void* p, size_t i) {
    if (f32) return ((const float*)p)[i];
    return bf2f(((const unsigned short*)p)[i]);
}
__device__ __forceinline__ float lo16(unsigned int u) { return __uint_as_float(u << 16); }
__device__ __forceinline__ float hi16(unsigned int u) { return __uint_as_float(u & 0xffff0000u); }

// MFMA wrapper
__device__ __forceinline__ floatx4 mf(short8 a, short8 b, floatx4 c) {
    return __builtin_amdgcn_mfma_f32_16x16x32_bf16(a, b, c, 0, 0, 0);
}

// A-fragment from packed-bf16 LDS buffer: row m, k-block kb, quad q.
__device__ __forceinline__ short8 ldA(const unsigned short* buf, int strideU,
                                      int m, int kb, int q) {
    const unsigned int* p = (const unsigned int*)buf + m * strideU + kb * 16 + q * 4;
    uint4 u = *(const uint4*)p;
    return __builtin_bit_cast(short8, u);
}
// B-fragment from prepacked weight buffer
__device__ __forceinline__ short8 ldB(const uint4* __restrict__ w, int idx) {
    return __builtin_bit_cast(short8, w[idx]);
}

// lgkm-only barrier: do NOT drain vmcnt/expcnt (prefetch loads + output stores
// stay in flight across phases). Memory clobbers on both sides keep the
// compiler from moving LDS ops across (rule #18-style hazards).
__device__ __forceinline__ void barx() {
    asm volatile("s_waitcnt lgkmcnt(0)" ::: "memory");
    __builtin_amdgcn_s_barrier();
    asm volatile("" ::: "memory");
}

// ---------- wbuf layout (units = 16B frags) ----------
#define OFF_FW   0        // 4t x 13kb
#define OFF_FWG  3328     // 4t x 2kb
#define OFF_GRU(G) (3840 + 4608*(G))   // r@+0(6kb) z@+1536(6kb) i@+3072(4kb) h@+4096(2kb)
#define OFF_WG(G)  (17664 + 512*(G))   // 4t x 2kb
#define OFF_SD   19200    // 8t x 10kb
#define OFF_SG   24320    // 8t x 4kb
#define OFF_OUT  26368    // 4t x 4kb
#define NFRAG    27392

// ---------- dtype detector ----------
__global__ void fargan_detect(const void* feats, int* flag) {
    const float* pf = (const float*)feats;
    int ok = 1;
    for (int f = 0; f < 50; ++f) {
        float v = pf[192 * NFRAMES + f];
        if (!(v >= 63.0f && v <= 301.0f)) { ok = 0; break; }
    }
    *flag = ok;
}

// ---------- weight prep: repack all seq weights into frag order ----------
__global__ __launch_bounds__(256) void fargan_prep(
    const int* __restrict__ flag,
    const void* Wfw, const void* Wfwg,
    const void* Wih1, const void* Whh1, const void* Wih2, const void* Whh2,
    const void* Wih3, const void* Whh3,
    const void* Wg1, const void* Wg2, const void* Wg3,
    const void* Wsg, const void* Wsd, const void* Wout,
    uint4* __restrict__ wbuf)
{
    int fi = blockIdx.x * 256 + threadIdx.x;
    if (fi >= NFRAG) return;
    int f32 = *flag;
    const void* mats[14] = {Wfw, Wfwg, Wih1, Whh1, Wih2, Whh2, Wih3, Whh3,
                            Wg1, Wg2, Wg3, Wsg, Wsd, Wout};
    const int NSEG = 20;
    const int sb[NSEG]  = {0,3328, 3840,5376,6912,7936, 8448,9984,11520,12544,
                           13056,14592,16128,17152, 17664,18176,18688, 19200,24320,26368};
    const int sa[NSEG]  = {0,1, 2,2,2,3, 4,4,4,5, 6,6,6,7, 8,9,10, 12,11,13};
    const int sbx[NSEG] = {-1,-1, 3,3,-1,-1, 5,5,-1,-1, 7,7,-1,-1, -1,-1,-1, -1,-1,-1};
    const int sro[NSEG] = {0,0, 0,64,128,128, 0,64,128,128, 0,64,128,128, 0,0,0, 0,0,0};
    const int skb[NSEG] = {13,2, 6,6,4,2, 6,6,4,2, 6,6,4,2, 2,2,2, 10,4,4};
    const int ska[NSEG] = {388,64, 128,128,128,64, 128,128,128,64, 128,128,128,64,
                           64,64,64, 320,128,128};
    const int skr[NSEG] = {388,64, 192,192,128,64, 192,192,128,64, 192,192,128,64,
                           64,64,64, 320,128,128};
    int s = 0;
    for (int i = 1; i < NSEG; ++i) if (fi >= sb[i]) s = i;
    int local = fi - sb[s];
    int ln = local & 15, lq = (local >> 4) & 3, tkb = local >> 6;
    int KB = skb[s];
    int kb = tkb % KB, tile = tkb / KB;
    int row = sro[s] + tile * 16 + ln;
    int Ka = ska[s], Kr = skr[s];
    union { unsigned short h[8]; uint4 v; } u;
#pragma unroll
    for (int j = 0; j < 8; ++j) {
        int k = kb * 32 + lq * 8 + j;
        unsigned short val = 0;
        if (k < Kr) {
            const void* m; size_t off;
            if (sbx[s] >= 0 && k >= Ka) { m = mats[sbx[s]]; off = (size_t)row * 64 + (k - Ka); }
            else                        { m = mats[sa[s]];  off = (size_t)row * Ka + k; }
            val = f32 ? f2bf(((const float*)m)[off]) : ((const unsigned short*)m)[off];
        }
        u.h[j] = val;
    }
    wbuf[fi] = u.v;
}

// ---------- prep: repack Wc1/2/3 transposed + bf16-pair packed ----------
__global__ __launch_bounds__(256) void fargan_prep_conv(
    const int* __restrict__ flag,
    const void* Wc1, const void* Wc2, const void* Wc3,
    unsigned int* __restrict__ wct)
{
    int idx = blockIdx.x * 256 + threadIdx.x;
    if (idx >= 131072) return;
    int f32 = *flag;
    const void* W; int n, k2;
    if (idx < 32768)      { W = Wc1; k2 = idx >> 8, n = idx & 255; }
    else if (idx < 65536) { W = Wc2; k2 = (idx - 32768) >> 8; n = idx & 255; }
    else                  { W = Wc3; k2 = (idx - 65536) >> 9; n = (idx - 65536) & 511; }
    size_t off = (size_t)n * 256 + 2 * k2;
    unsigned int v;
    if (f32) {
        const float* p = (const float*)W + off;
        v = packbf(p[0], p[1]);
    } else {
        v = *(const unsigned int*)((const unsigned short*)W + off);
    }
    wct[idx] = v;
}

// ---------- kernel 1: frame conv -> bf16 output cb16[b][f][k*128+j] ----------
// 4 frames per block: the 512 KB packed weight stream is reused 4x, cutting
// L2/L3 weight traffic from ~3.2 GB to ~0.8 GB.
template<bool F32>
__device__ __forceinline__ void conv_body(
    const void* __restrict__ feats, const void* __restrict__ gfeat,
    const unsigned int* __restrict__ wct, unsigned short* __restrict__ cb16)
{
    int blk = blockIdx.x;
    int b = blk / 25, fq = blk - b * 25;
    int f0 = fq * 4;
    int t = threadIdx.x;
    __shared__ float xa[4][256], xb[4][256];

#pragma unroll
    for (int j = 0; j < 4; ++j) {
        float v;
        if (t < 192) v = ld1f(F32 ? 1 : 0, feats, (size_t)b * (NF * NFRAMES) + t * NFRAMES + f0 + j);
        else         v = ld1f(F32 ? 1 : 0, gfeat, (size_t)b * 64 + (t - 192));
        xa[j][t] = v;
    }
    __syncthreads();

    const unsigned int* w1 = wct;
    const unsigned int* w2 = wct + 32768;
    const unsigned int* w3 = wct + 65536;

    float a0[4], a1[4], b0[4], b1[4];
#pragma unroll
    for (int j = 0; j < 4; ++j) { a0[j] = 0.f; a1[j] = 0.f; }
#pragma unroll 4
    for (int k2 = 0; k2 < 128; ++k2) {
        unsigned int u = w1[k2 * 256 + t];
        float lo = lo16(u), hi = hi16(u);
#pragma unroll
        for (int j = 0; j < 4; ++j) {
            a0[j] = fmaf(lo, xa[j][2 * k2], a0[j]);
            a1[j] = fmaf(hi, xa[j][2 * k2 + 1], a1[j]);
        }
    }
#pragma unroll
    for (int j = 0; j < 4; ++j) xb[j][t] = ftanh(a0[j] + a1[j]);
    __syncthreads();

#pragma unroll
    for (int j = 0; j < 4; ++j) { a0[j] = 0.f; a1[j] = 0.f; }
#pragma unroll 4
    for (int k2 = 0; k2 < 128; ++k2) {
        unsigned int u = w2[k2 * 256 + t];
        float lo = lo16(u), hi = hi16(u);
#pragma unroll
        for (int j = 0; j < 4; ++j) {
            a0[j] = fmaf(lo, xb[j][2 * k2], a0[j]);
            a1[j] = fmaf(hi, xb[j][2 * k2 + 1], a1[j]);
        }
    }
    __syncthreads();
#pragma unroll
    for (int j = 0; j < 4; ++j) xa[j][t] = ftanh(a0[j] + a1[j]);
    __syncthreads();

#pragma unroll
    for (int j = 0; j < 4; ++j) { a0[j] = 0.f; a1[j] = 0.f; b0[j] = 0.f; b1[j] = 0.f; }
#pragma unroll 4
    for (int k2 = 0; k2 < 128; ++k2) {
        unsigned int u  = w3[k2 * 512 + t];
        unsigned int u2 = w3[k2 * 512 + t + 256];
        float lo = lo16(u), hi = hi16(u), lo2 = lo16(u2), hi2 = hi16(u2);
#pragma unroll
        for (int j = 0; j < 4; ++j) {
            a0[j] = fmaf(lo,  xa[j][2 * k2],     a0[j]);
            a1[j] = fmaf(hi,  xa[j][2 * k2 + 1], a1[j]);
            b0[j] = fmaf(lo2, xa[j][2 * k2],     b0[j]);
            b1[j] = fmaf(hi2, xa[j][2 * k2 + 1], b1[j]);
        }
    }
    int e0 = t, e1 = t + 256;
#pragma unroll
    for (int j = 0; j < 4; ++j) {
        unsigned short* co = cb16 + ((size_t)b * NFRAMES + f0 + j) * 512;
        co[(e0 & 3) * 128 + (e0 >> 2)] = f2bf(ftanh(a0[j] + a1[j]));
        co[(e1 & 3) * 128 + (e1 >> 2)] = f2bf(ftanh(b0[j] + b1[j]));
    }
}

__global__ __launch_bounds__(256) void fargan_conv(
    const void* feats, const void* gfeat,
    const int* flag, const unsigned int* wct, unsigned short* cb16)
{
    if (*flag) conv_body<true>(feats, gfeat, wct, cb16);
    else       conv_body<false>(feats, gfeat, wct, cb16);
}

// ---------- kernel 2: sequential recurrence ----------
// Phase-skewed schedule: every K-segment whose input is already visible is
// computed one-or-more phases early and carried in register accumulators
// across the barrier, so each phase's in-phase ds_read -> MFMA chain shrinks:
//   FW:   10/13 kb's in BUILD (feat2s/ps/sfw staged during previous OUT)
//   GRUg: ps+state segments (12 of 18 MFMAs) in the preceding FWG/GLU phase
//   SD:   ps segment in BUILD; fw/o1/o2 in GRU phases (as before); o3 last.
// Barriers are lgkm-only (prefetch + output stores stay in flight).

__global__ __launch_bounds__(256, 1) void fargan_seq(
    const void* __restrict__ feats, const void* __restrict__ prev_in,
    const int* __restrict__ flag, const unsigned short* __restrict__ cb16,
    const uint4* __restrict__ wbuf, void* __restrict__ outp)
{
    const int t = threadIdx.x;
    const int b0 = blockIdx.x * RPW;
    const int lane = t & 63, w = t >> 6;
    const int lq = lane >> 4, ln = lane & 15;
    const int nj = 16 * w + ln;            // n for 64-wide layers
    const int f32 = *flag;

    // ---- LDS (~142.6 KB) ----
    __shared__ __align__(16) unsigned short hist[RPW * 520];   // bf16 ring, mod-512
    __shared__ __align__(16) unsigned short catb[RPW * 424];   // [feat2s|ps|look|sfw|pad]
    __shared__ __align__(16) unsigned short xg  [RPW * 200];   // [in0|ps|s]
    __shared__ __align__(16) unsigned short skx [RPW * 328];   // [o1|o2|o3|fw|ps]
    __shared__ __align__(16) unsigned short sdbb[RPW * 136];
    __shared__ __align__(16) unsigned short sobb[RPW * 136];
    __shared__ __align__(16) unsigned short v64 [RPW * 72];    // vpre / svp (merged)
    __shared__ __align__(16) unsigned short wsd[128 * 328];    // Wsd, 164u stride
    __shared__ int period_s[RPW];

    // ---- resident B-fragments, coalesced preload from wbuf ----
    short8 Bfw[13], Bfwg[2], Bout[4];
    short8 Br[3][6], Bz[3][6], Bi[3][4], Bh[3][2], Bg[3][2];
    short8 Bsg[2][4];
#pragma unroll
    for (int kb = 0; kb < 13; ++kb) Bfw[kb] = ldB(wbuf, OFF_FW + (w * 13 + kb) * 64 + lane);
#pragma unroll
    for (int kb = 0; kb < 2; ++kb)  Bfwg[kb] = ldB(wbuf, OFF_FWG + (w * 2 + kb) * 64 + lane);
#pragma unroll
    for (int G = 0; G < 3; ++G) {
        const int OR = OFF_GRU(G), OZ = OR + 1536, OI = OR + 3072, OH = OR + 4096;
#pragma unroll
        for (int kb = 0; kb < 6; ++kb) {
            Br[G][kb] = ldB(wbuf, OR + (w * 6 + kb) * 64 + lane);
            Bz[G][kb] = ldB(wbuf, OZ + (w * 6 + kb) * 64 + lane);
        }
#pragma unroll
        for (int kb = 0; kb < 4; ++kb) Bi[G][kb] = ldB(wbuf, OI + (w * 4 + kb) * 64 + lane);
#pragma unroll
        for (int kb = 0; kb < 2; ++kb) {
            Bh[G][kb] = ldB(wbuf, OH + (w * 2 + kb) * 64 + lane);
            Bg[G][kb] = ldB(wbuf, OFF_WG(G) + (w * 2 + kb) * 64 + lane);
        }
    }
#pragma unroll
    for (int tile = 0; tile < 2; ++tile)
#pragma unroll
        for (int kb = 0; kb < 4; ++kb)
            Bsg[tile][kb] = ldB(wbuf, OFF_SG + ((2 * w + tile) * 4 + kb) * 64 + lane);
#pragma unroll
    for (int kb = 0; kb < 4; ++kb) Bout[kb] = ldB(wbuf, OFF_OUT + (w * 4 + kb) * 64 + lane);

    // ---- Wsd -> LDS from wbuf ----
    for (int fi = t; fi < 8 * 10 * 64; fi += 256) {
        int lane2 = fi & 63, tkb = fi >> 6;
        int kb = tkb % 10, tile = tkb / 10;
        int lq2 = lane2 >> 4, ln2 = lane2 & 15;
        int row = tile * 16 + ln2;
        uint4 v = wbuf[OFF_SD + fi];
        *(uint4*)((unsigned int*)wsd + row * 164 + kb * 16 + lq2 * 4) = v;
    }

    // ---- zero init LDS state + hist fill ----
    for (int i = t; i < RPW * 424; i += 256) catb[i] = 0;
    for (int i = t; i < RPW * 200; i += 256) xg[i] = 0;
    for (int i = t; i < RPW * 328; i += 256) skx[i] = 0;
    for (int i = t; i < RPW * 136; i += 256) { sdbb[i] = 0; sobb[i] = 0; }
    for (int i = t; i < RPW * 72;  i += 256) v64[i] = 0;
    for (int i = t; i < RPW * 512; i += 256) {
        int row = i >> 9, c = i & 511;
        hist[row * 520 + c] = f2bf(ld1f(f32, prev_in, (size_t)(b0 + row) * LPREV + c));
    }
    __syncthreads();
    // initial prev_sub slots (step 0): window[448..511] of prev_in
    for (int i = t; i < RPW * 64; i += 256) {
        int row = i >> 6, c = i & 63;
        unsigned short hh = hist[row * 520 + 448 + c];
        catb[row * 424 + 128 + c] = hh;
        skx [row * 328 + 256 + c] = hh;
        xg  [row * 200 + 64  + c] = hh;
    }

    // GRU states in C-layout registers
    floatx4 svr[3];
#pragma unroll
    for (int G = 0; G < 3; ++G) svr[G] = (floatx4){0.f, 0.f, 0.f, 0.f};

    // ---- staging thread mapping (16 threads/row, 8 bf16 each) ----
    const int prow = t >> 4, px16 = t & 15, pe8 = (t & 15) * 8;
    // write feat2s(step 0) synchronously; prefetch feat2s(step 1)
    uint4 pfc;
    {
        uint4 u0 = *(const uint4*)(cb16 + ((size_t)(b0 + prow) * NFRAMES + 0) * 512 + 0 * 128 + pe8);
        *(uint4*)((unsigned int*)catb + prow * 212 + (pe8 >> 1)) = u0;
        pfc = *(const uint4*)(cb16 + ((size_t)(b0 + prow) * NFRAMES + 0) * 512 + 1 * 128 + pe8);
    }
    float pper = 0.f;
    if (t < RPW) {
        pper = ld1f(f32, feats, (size_t)(b0 + t) * (NF * NFRAMES) + (NF - 1) * NFRAMES + 0);
        period_s[t] = (int)rintf(pper);
    }
    __syncthreads();

    const floatx4 z4 = {0.f, 0.f, 0.f, 0.f};
    int base = 0;
    for (int f = 0; f < NFRAMES; ++f) {
        for (int kk = 0; kk < NSUB; ++kk) {
            const int n0 = 32 * w + ln, n1 = n0 + 16;
            floatx4 SD00 = z4, SD01 = z4, SD10 = z4, SD11 = z4;
            floatx4 C0 = z4, C1 = z4, C2 = z4, C3 = z4;   // FW partials
            floatx4 Cr, Cz, Ci, Ch;                       // GRU partials

            // ====== Phase A: lookback gather + FW partials (kb 0-5,9-12)
            //                 + SD ps partials (skx kb 8,9) ======
            {
                int per = period_s[prow];
#pragma unroll
                for (int ii = 0; ii < 5; ++ii) {
                    int i = px16 * 5 + ii;
                    if (i < 68) {
                        int idx = LPREV - per + i - 2;
                        if (idx >= LPREV) idx -= per;
                        catb[prow * 424 + 192 + i] = hist[prow * 520 + ((base + idx) & 511)];
                    }
                }
#pragma unroll
                for (int kb = 0; kb < 13; ++kb) {
                    if (kb >= 6 && kb <= 8) continue;   // lookback-dependent, done in B
                    short8 a = ldA(catb, 212, ln, kb, lq);
                    switch (kb & 3) {
                        case 0: C0 = mf(a, Bfw[kb], C0); break;
                        case 1: C1 = mf(a, Bfw[kb], C1); break;
                        case 2: C2 = mf(a, Bfw[kb], C2); break;
                        default: C3 = mf(a, Bfw[kb], C3); break;
                    }
                }
#pragma unroll
                for (int j = 0; j < 2; ++j) {
                    int kb = 8 + j;
                    short8 a   = ldA(skx, 164, ln, kb, lq);
                    short8 b0f = ldA(wsd, 164, n0, kb, lq);
                    short8 b1f = ldA(wsd, 164, n1, kb, lq);
                    if (kb & 1) { SD01 = mf(a, b0f, SD01); SD11 = mf(a, b1f, SD11); }
                    else        { SD00 = mf(a, b0f, SD00); SD10 = mf(a, b1f, SD10); }
                }
            }
            barx();                                        // A

            // ====== Phase B: FW finish (kb 6-8) + tanh -> v64
            //                 + GRU1 partials (xg kb 2-5: ps + s1) ======
            {
#pragma unroll
                for (int kb = 6; kb <= 8; ++kb) {
                    short8 a = ldA(catb, 212, ln, kb, lq);
                    switch (kb & 3) {
                        case 0: C0 = mf(a, Bfw[kb], C0); break;
                        case 1: C1 = mf(a, Bfw[kb], C1); break;
                        case 2: C2 = mf(a, Bfw[kb], C2); break;
                        default: C3 = mf(a, Bfw[kb], C3); break;
                    }
                }
                Cr = z4; Cz = z4; Ci = z4; Ch = z4;
#pragma unroll
                for (int kb = 2; kb < 6; ++kb) {
                    short8 a = ldA(xg, 100, ln, kb, lq);
                    Cr = mf(a, Br[0][kb], Cr);
                    Cz = mf(a, Bz[0][kb], Cz);
                    if (kb < 4) Ci = mf(a, Bi[0][kb], Ci);
                    else        Ch = mf(a, Bh[0][kb - 4], Ch);
                }
#pragma unroll
                for (int r = 0; r < 4; ++r) {
                    int m = 4 * lq + r;
                    v64[m * 72 + nj] = f2bf(ftanh((C0[r] + C1[r]) + (C2[r] + C3[r])));
                }
            }
            barx();                                        // B

            // ====== Phase C: FWG glu -> fw; write skx fw + xg in0 ======
            {
                floatx4 C = z4;
#pragma unroll
                for (int kb = 0; kb < 2; ++kb)
                    C = mf(ldA(v64, 36, ln, kb, lq), Bfwg[kb], C);
#pragma unroll
                for (int r = 0; r < 4; ++r) {
                    int m = 4 * lq + r;
                    float vp = bf2f(v64[m * 72 + nj]);
                    unsigned short ob = f2bf(vp * fsig(C[r]));
                    skx[m * 328 + 192 + nj] = ob;   // fw slot
                    xg [m * 200 + nj]       = ob;   // in0 for GRU1
                }
            }
            barx();                                        // C

            // ====== GRU finish + GLU (+ next-GRU partials) x3 ======
#pragma unroll
            for (int G = 0; G < 3; ++G) {
                // --- GRU finish: xg kb0,1 (in0) + SD segment + elementwise ---
                {
#pragma unroll
                    for (int kb = 0; kb < 2; ++kb) {
                        short8 a = ldA(xg, 100, ln, kb, lq);
                        Cr = mf(a, Br[G][kb], Cr);
                        Cz = mf(a, Bz[G][kb], Cz);
                        Ci = mf(a, Bi[G][kb], Ci);
                    }
                    // SD segments now visible: G0: fw(kb6,7); G1: o1(kb0,1); G2: o2(kb2,3)
                    const int kbs = (G == 0) ? 6 : (G == 1) ? 0 : 2;
#pragma unroll
                    for (int j = 0; j < 2; ++j) {
                        int kb = kbs + j;
                        short8 a   = ldA(skx, 164, ln, kb, lq);
                        short8 b0f = ldA(wsd, 164, n0, kb, lq);
                        short8 b1f = ldA(wsd, 164, n1, kb, lq);
                        if (kb & 1) { SD01 = mf(a, b0f, SD01); SD11 = mf(a, b1f, SD11); }
                        else        { SD00 = mf(a, b0f, SD00); SD10 = mf(a, b1f, SD10); }
                    }
#pragma unroll
                    for (int r = 0; r < 4; ++r) {
                        int m = 4 * lq + r;
                        float rr = fsig(Cr[r]);
                        float zz = fsig(Cz[r]);
                        float nn = ftanh(Ci[r] + rr * Ch[r]);
                        float sn = fmaf(zz, svr[G][r] - nn, nn);
                        svr[G][r] = sn;
                        v64[m * 72 + nj] = f2bf(sn);
                        // stage next GRU's state for the partials in the GLU phase
                        if (G < 2) xg[m * 200 + 128 + nj] = f2bf(svr[G + 1][r]);
                    }
                }
                barx();                                    // D/F/H
                // --- GLU + GRU(G+1) partials (xg kb2-5: ps + s_{G+1}) ---
                {
                    floatx4 C = z4;
#pragma unroll
                    for (int kb = 0; kb < 2; ++kb)
                        C = mf(ldA(v64, 36, ln, kb, lq), Bg[G][kb], C);
                    if (G < 2) {
                        Cr = z4; Cz = z4; Ci = z4; Ch = z4;
#pragma unroll
                        for (int kb = 2; kb < 6; ++kb) {
                            short8 a = ldA(xg, 100, ln, kb, lq);
                            Cr = mf(a, Br[G + 1][kb], Cr);
                            Cz = mf(a, Bz[G + 1][kb], Cz);
                            if (kb < 4) Ci = mf(a, Bi[G + 1][kb], Ci);
                            else        Ch = mf(a, Bh[G + 1][kb - 4], Ch);
                        }
                    }
#pragma unroll
                    for (int r = 0; r < 4; ++r) {
                        int m = 4 * lq + r;
                        unsigned short ob = f2bf(svr[G][r] * fsig(C[r]));
                        skx[m * 328 + G * 64 + nj] = ob;
                        if (G < 2) xg[m * 200 + nj] = ob;   // in0 for next GRU
                    }
                }
                barx();                                    // E/G/I
            }

            // ====== Phase J: SD finish — only o3 (skx kb4,5) ======
            {
#pragma unroll
                for (int j = 0; j < 2; ++j) {
                    int kb = 4 + j;
                    short8 a   = ldA(skx, 164, ln, kb, lq);
                    short8 b0f = ldA(wsd, 164, n0, kb, lq);
                    short8 b1f = ldA(wsd, 164, n1, kb, lq);
                    if (kb & 1) { SD01 = mf(a, b0f, SD01); SD11 = mf(a, b1f, SD11); }
                    else        { SD00 = mf(a, b0f, SD00); SD10 = mf(a, b1f, SD10); }
                }
#pragma unroll
                for (int r = 0; r < 4; ++r) {
                    int m = 4 * lq + r;
                    sdbb[m * 136 + n0] = f2bf(ftanh(SD00[r] + SD01[r]));
                    sdbb[m * 136 + n1] = f2bf(ftanh(SD10[r] + SD11[r]));
                }
            }
            barx();                                        // J

            // ====== Phase K: SG (glu) ======
            {
                floatx4 Ca = z4, Cb = z4, Cc = z4, Cd = z4;
#pragma unroll
                for (int kb = 0; kb < 4; ++kb) {
                    short8 a = ldA(sdbb, 68, ln, kb, lq);
                    if (kb & 1) { Cb = mf(a, Bsg[0][kb], Cb); Cd = mf(a, Bsg[1][kb], Cd); }
                    else        { Ca = mf(a, Bsg[0][kb], Ca); Cc = mf(a, Bsg[1][kb], Cc); }
                }
#pragma unroll
                for (int r = 0; r < 4; ++r) {
                    int m = 4 * lq + r;
                    float s0 = bf2f(sdbb[m * 136 + n0]);
                    float s1 = bf2f(sdbb[m * 136 + n1]);
                    sobb[m * 136 + n0] = f2bf(s0 * fsig(Ca[r] + Cb[r]));
                    sobb[m * 136 + n1] = f2bf(s1 * fsig(Cc[r] + Cd[r]));
                }
            }
            barx();                                        // K

            // ====== Phase L: OUT (tanh) + all next-step staging ======
            {
                floatx4 Ca = z4, Cb = z4;
#pragma unroll
                for (int kb = 0; kb < 4; ++kb) {
                    short8 a = ldA(sobb, 68, ln, kb, lq);
                    if (kb & 1) Cb = mf(a, Bout[kb], Cb);
                    else        Ca = mf(a, Bout[kb], Ca);
                }
                // feat2s(step s) -> sfw, feat2s(step s+1) <- pfc, prefetch s+2
                {
                    unsigned int* cat32 = (unsigned int*)catb;
                    int cb = prow * 212;
                    int u0 = pe8 >> 1;
                    unsigned int o0 = cat32[cb + u0 + 0];
                    unsigned int o1 = cat32[cb + u0 + 1];
                    unsigned int o2 = cat32[cb + u0 + 2];
                    unsigned int o3 = cat32[cb + u0 + 3];
                    cat32[cb + 130 + u0 + 0] = o0;
                    cat32[cb + 130 + u0 + 1] = o1;
                    cat32[cb + 130 + u0 + 2] = o2;
                    cat32[cb + 130 + u0 + 3] = o3;
                    *(uint4*)(cat32 + cb + u0) = pfc;
                    int sN = f * 4 + kk + 2;
                    if (sN > NFRAMES * 4 - 1) sN = NFRAMES * 4 - 1;
                    pfc = *(const uint4*)(cb16
                        + ((size_t)(b0 + prow) * NFRAMES + (sN >> 2)) * 512 + (sN & 3) * 128 + pe8);
                }
                // period staging: load next frame's period early, publish at kk==3
                if (kk == 0 && t < RPW) {
                    int fN = (f + 1 < NFRAMES) ? f + 1 : f;
                    pper = ld1f(f32, feats,
                                (size_t)(b0 + t) * (NF * NFRAMES) + (NF - 1) * NFRAMES + fN);
                }
                if (kk == 3 && t < RPW) period_s[t] = (int)rintf(pper);
#pragma unroll
                for (int r = 0; r < 4; ++r) {
                    int m = 4 * lq + r;
                    float ov = ftanh(Ca[r] + Cb[r]);
                    unsigned short ob = f2bf(ov);
                    hist[m * 520 + ((base + nj) & 511)] = ob;
                    catb[m * 424 + 128 + nj] = ob;             // ps for FW
                    skx [m * 328 + 256 + nj] = ob;             // ps for SD
                    xg  [m * 200 + 64  + nj] = ob;             // ps for GRUs
                    xg  [m * 200 + 128 + nj] = f2bf(svr[0][r]); // s1 for next GRU1 partials
                    size_t oi = (size_t)(b0 + m) * (NFRAMES * NSUB * SS)
                              + f * (NSUB * SS) + kk * SS + nj;
                    if (f32) ((float*)outp)[oi] = ov;
                    else     ((unsigned short*)outp)[oi] = ob;
                }
            }
            barx();                                        // L

            base += SS;
        }
    }
}

// ---------- launch ----------
extern "C" void kernel_launch(void* const* d_in, const int* in_sizes, int n_in,
                              void* d_out, int out_size, void* d_ws, size_t ws_size,
                              hipStream_t stream) {
    const void* feats = d_in[0];
    const void* gfeat = d_in[1];
    const void* prev  = d_in[2];
    const void* Wc1   = d_in[3];
    const void* Wc2   = d_in[4];
    const void* Wc3   = d_in[5];
    const void* Wfw   = d_in[6];
    const void* Wfwg  = d_in[7];
    const void* Wih1  = d_in[8];
    const void* Whh1  = d_in[9];
    const void* Wih2  = d_in[10];
    const void* Whh2  = d_in[11];
    const void* Wih3  = d_in[12];
    const void* Whh3  = d_in[13];
    const void* Wg1   = d_in[14];
    const void* Wg2   = d_in[15];
    const void* Wg3   = d_in[16];
    const void* Wsg   = d_in[17];
    const void* Wsd   = d_in[18];
    const void* Wout  = d_in[19];

    int*            flag = (int*)d_ws;                                      // @0
    unsigned short* cb16 = (unsigned short*)((char*)d_ws + 256);            // 6,553,600 B
    unsigned int*   wct  = (unsigned int*)((char*)d_ws + 256 + 6553600);    // 524,288 B
    uint4*          wbuf = (uint4*)((char*)d_ws + 256 + 6553600 + 524288);  // 438,272 B

    fargan_detect<<<1, 1, 0, stream>>>(feats, flag);
    fargan_prep<<<(NFRAG + 255) / 256, 256, 0, stream>>>(flag, Wfw, Wfwg,
        Wih1, Whh1, Wih2, Whh2, Wih3, Whh3, Wg1, Wg2, Wg3, Wsg, Wsd, Wout, wbuf);
    fargan_prep_conv<<<512, 256, 0, stream>>>(flag, Wc1, Wc2, Wc3, wct);
    fargan_conv<<<BATCH * 25, 256, 0, stream>>>(feats, gfeat, flag, wct, cb16);
    fargan_seq<<<BATCH / RPW, 256, 0, stream>>>(feats, prev, flag, cb16, wbuf, d_out);
}

// Round 2
// 2192.421 us; speedup vs baseline: 1.1953x; 1.1370x over previous
//
#include <hip/hip_runtime.h>
#include <hip/hip_bf16.h>

// FARGAN vocoder on MI355X. Sizes fixed by the reference:
#define SS      64
#define NSUB    4
#define LPREV   512
#define NF      193
#define NFRAMES 100
#define BATCH   64
#define RPW     16     // batch rows per workgroup (MFMA M)

typedef __attribute__((ext_vector_type(8))) short   short8;   // 8 bf16 (4 VGPRs)
typedef __attribute__((ext_vector_type(4))) float   floatx4;  // MFMA C/D

// ---------- scalar helpers ----------
__device__ __forceinline__ float bf2f(unsigned short u) {
    return __uint_as_float(((unsigned int)u) << 16);
}
__device__ __forceinline__ unsigned short f2bf(float x) {
    unsigned int u = __float_as_uint(x);
    return (unsigned short)((u + 0x7fffu + ((u >> 16) & 1u)) >> 16);
}
__device__ __forceinline__ unsigned int packbf(float a, float b) {
    return (unsigned int)f2bf(a) | ((unsigned int)f2bf(b) << 16);
}
__device__ __forceinline__ float fexp2(float x) {
#if __has_builtin(__builtin_amdgcn_exp2f)
    return __builtin_amdgcn_exp2f(x);
#else
    return exp2f(x);
#endif
}
__device__ __forceinline__ float frcp(float x) {
#if __has_builtin(__builtin_amdgcn_rcpf)
    return __builtin_amdgcn_rcpf(x);
#else
    return 1.0f / x;
#endif
}
__device__ __forceinline__ float fsig(float x) {
    return frcp(1.0f + fexp2(-1.442695041f * x));
}
__device__ __forceinline__ float ftanh(float x) {
    return fmaf(2.0f, frcp(1.0f + fexp2(-2.885390082f * x)), -1.0f);
}
__device__ __forceinline__ float ld1f(int f32, const void* p, size_t i) {
    if (f32) return ((const float*)p)[i];
    return bf2f(((const unsigned short*)p)[i]);
}
__device__ __forceinline__ float lo16(unsigned int u) { return __uint_as_float(u << 16); }
__device__ __forceinline__ float hi16(unsigned int u) { return __uint_as_float(u & 0xffff0000u); }

// MFMA wrapper
__device__ __forceinline__ floatx4 mf(short8 a, short8 b, floatx4 c) {
    return __builtin_amdgcn_mfma_f32_16x16x32_bf16(a, b, c, 0, 0, 0);
}

// A-fragment from packed-bf16 LDS buffer: row m, k-block kb, quad q.
__device__ __forceinline__ short8 ldA(const unsigned short* buf, int strideU,
                                      int m, int kb, int q) {
    const unsigned int* p = (const unsigned int*)buf + m * strideU + kb * 16 + q * 4;
    uint4 u = *(const uint4*)p;
    return __builtin_bit_cast(short8, u);
}
// B-fragment from prepacked weight buffer
__device__ __forceinline__ short8 ldB(const uint4* __restrict__ w, int idx) {
    return __builtin_bit_cast(short8, w[idx]);
}

// lgkm-only barrier: do NOT drain vmcnt (prefetch loads + output stores stay
// in flight). Memory clobbers keep the compiler from moving LDS ops across.
__device__ __forceinline__ void barx() {
    asm volatile("s_waitcnt lgkmcnt(0)" ::: "memory");
    __builtin_amdgcn_s_barrier();
    asm volatile("" ::: "memory");
}

// ---------- wbuf layout (units = 16B frags) ----------
#define OFF_FW   0        // 4t x 13kb
#define OFF_FWG  3328     // 4t x 2kb
#define OFF_GRU(G) (3840 + 4608*(G))   // r@+0(6kb) z@+1536(6kb) i@+3072(4kb) h@+4096(2kb)
#define OFF_WG(G)  (17664 + 512*(G))   // 4t x 2kb
#define OFF_SD   19200    // 8t x 10kb
#define OFF_SG   24320    // 8t x 4kb
#define OFF_OUT  26368    // 4t x 4kb
#define NFRAG    27392

// ---------- dtype detector ----------
__global__ void fargan_detect(const void* feats, int* flag) {
    const float* pf = (const float*)feats;
    int ok = 1;
    for (int f = 0; f < 50; ++f) {
        float v = pf[192 * NFRAMES + f];
        if (!(v >= 63.0f && v <= 301.0f)) { ok = 0; break; }
    }
    *flag = ok;
}

// ---------- weight prep: repack all seq weights into frag order ----------
__global__ __launch_bounds__(256) void fargan_prep(
    const int* __restrict__ flag,
    const void* Wfw, const void* Wfwg,
    const void* Wih1, const void* Whh1, const void* Wih2, const void* Whh2,
    const void* Wih3, const void* Whh3,
    const void* Wg1, const void* Wg2, const void* Wg3,
    const void* Wsg, const void* Wsd, const void* Wout,
    uint4* __restrict__ wbuf)
{
    int fi = blockIdx.x * 256 + threadIdx.x;
    if (fi >= NFRAG) return;
    int f32 = *flag;
    const void* mats[14] = {Wfw, Wfwg, Wih1, Whh1, Wih2, Whh2, Wih3, Whh3,
                            Wg1, Wg2, Wg3, Wsg, Wsd, Wout};
    const int NSEG = 20;
    const int sb[NSEG]  = {0,3328, 3840,5376,6912,7936, 8448,9984,11520,12544,
                           13056,14592,16128,17152, 17664,18176,18688, 19200,24320,26368};
    const int sa[NSEG]  = {0,1, 2,2,2,3, 4,4,4,5, 6,6,6,7, 8,9,10, 12,11,13};
    const int sbx[NSEG] = {-1,-1, 3,3,-1,-1, 5,5,-1,-1, 7,7,-1,-1, -1,-1,-1, -1,-1,-1};
    const int sro[NSEG] = {0,0, 0,64,128,128, 0,64,128,128, 0,64,128,128, 0,0,0, 0,0,0};
    const int skb[NSEG] = {13,2, 6,6,4,2, 6,6,4,2, 6,6,4,2, 2,2,2, 10,4,4};
    const int ska[NSEG] = {388,64, 128,128,128,64, 128,128,128,64, 128,128,128,64,
                           64,64,64, 320,128,128};
    const int skr[NSEG] = {388,64, 192,192,128,64, 192,192,128,64, 192,192,128,64,
                           64,64,64, 320,128,128};
    int s = 0;
    for (int i = 1; i < NSEG; ++i) if (fi >= sb[i]) s = i;
    int local = fi - sb[s];
    int ln = local & 15, lq = (local >> 4) & 3, tkb = local >> 6;
    int KB = skb[s];
    int kb = tkb % KB, tile = tkb / KB;
    int row = sro[s] + tile * 16 + ln;
    int Ka = ska[s], Kr = skr[s];
    union { unsigned short h[8]; uint4 v; } u;
#pragma unroll
    for (int j = 0; j < 8; ++j) {
        int k = kb * 32 + lq * 8 + j;
        unsigned short val = 0;
        if (k < Kr) {
            const void* m; size_t off;
            if (sbx[s] >= 0 && k >= Ka) { m = mats[sbx[s]]; off = (size_t)row * 64 + (k - Ka); }
            else                        { m = mats[sa[s]];  off = (size_t)row * Ka + k; }
            val = f32 ? f2bf(((const float*)m)[off]) : ((const unsigned short*)m)[off];
        }
        u.h[j] = val;
    }
    wbuf[fi] = u.v;
}

// ---------- prep: repack Wc1/2/3 transposed + bf16-pair packed ----------
__global__ __launch_bounds__(256) void fargan_prep_conv(
    const int* __restrict__ flag,
    const void* Wc1, const void* Wc2, const void* Wc3,
    unsigned int* __restrict__ wct)
{
    int idx = blockIdx.x * 256 + threadIdx.x;
    if (idx >= 131072) return;
    int f32 = *flag;
    const void* W; int n, k2;
    if (idx < 32768)      { W = Wc1; k2 = idx >> 8, n = idx & 255; }
    else if (idx < 65536) { W = Wc2; k2 = (idx - 32768) >> 8; n = idx & 255; }
    else                  { W = Wc3; k2 = (idx - 65536) >> 9; n = (idx - 65536) & 511; }
    size_t off = (size_t)n * 256 + 2 * k2;
    unsigned int v;
    if (f32) {
        const float* p = (const float*)W + off;
        v = packbf(p[0], p[1]);
    } else {
        v = *(const unsigned int*)((const unsigned short*)W + off);
    }
    wct[idx] = v;
}

// ---------- kernel 1: frame conv -> bf16 output cb16[b][f][k*128+j] ----------
template<bool F32>
__device__ __forceinline__ void conv_body(
    const void* __restrict__ feats, const void* __restrict__ gfeat,
    const unsigned int* __restrict__ wct, unsigned short* __restrict__ cb16)
{
    int blk = blockIdx.x;
    int b = blk / 25, fq = blk - b * 25;
    int f0 = fq * 4;
    int t = threadIdx.x;
    __shared__ float xa[4][256], xb[4][256];

#pragma unroll
    for (int j = 0; j < 4; ++j) {
        float v;
        if (t < 192) v = ld1f(F32 ? 1 : 0, feats, (size_t)b * (NF * NFRAMES) + t * NFRAMES + f0 + j);
        else         v = ld1f(F32 ? 1 : 0, gfeat, (size_t)b * 64 + (t - 192));
        xa[j][t] = v;
    }
    __syncthreads();

    const unsigned int* w1 = wct;
    const unsigned int* w2 = wct + 32768;
    const unsigned int* w3 = wct + 65536;

    float a0[4], a1[4], b0[4], b1[4];
#pragma unroll
    for (int j = 0; j < 4; ++j) { a0[j] = 0.f; a1[j] = 0.f; }
#pragma unroll 4
    for (int k2 = 0; k2 < 128; ++k2) {
        unsigned int u = w1[k2 * 256 + t];
        float lo = lo16(u), hi = hi16(u);
#pragma unroll
        for (int j = 0; j < 4; ++j) {
            a0[j] = fmaf(lo, xa[j][2 * k2], a0[j]);
            a1[j] = fmaf(hi, xa[j][2 * k2 + 1], a1[j]);
        }
    }
#pragma unroll
    for (int j = 0; j < 4; ++j) xb[j][t] = ftanh(a0[j] + a1[j]);
    __syncthreads();

#pragma unroll
    for (int j = 0; j < 4; ++j) { a0[j] = 0.f; a1[j] = 0.f; }
#pragma unroll 4
    for (int k2 = 0; k2 < 128; ++k2) {
        unsigned int u = w2[k2 * 256 + t];
        float lo = lo16(u), hi = hi16(u);
#pragma unroll
        for (int j = 0; j < 4; ++j) {
            a0[j] = fmaf(lo, xb[j][2 * k2], a0[j]);
            a1[j] = fmaf(hi, xb[j][2 * k2 + 1], a1[j]);
        }
    }
    __syncthreads();
#pragma unroll
    for (int j = 0; j < 4; ++j) xa[j][t] = ftanh(a0[j] + a1[j]);
    __syncthreads();

#pragma unroll
    for (int j = 0; j < 4; ++j) { a0[j] = 0.f; a1[j] = 0.f; b0[j] = 0.f; b1[j] = 0.f; }
#pragma unroll 4
    for (int k2 = 0; k2 < 128; ++k2) {
        unsigned int u  = w3[k2 * 512 + t];
        unsigned int u2 = w3[k2 * 512 + t + 256];
        float lo = lo16(u), hi = hi16(u), lo2 = lo16(u2), hi2 = hi16(u2);
#pragma unroll
        for (int j = 0; j < 4; ++j) {
            a0[j] = fmaf(lo,  xa[j][2 * k2],     a0[j]);
            a1[j] = fmaf(hi,  xa[j][2 * k2 + 1], a1[j]);
            b0[j] = fmaf(lo2, xa[j][2 * k2],     b0[j]);
            b1[j] = fmaf(hi2, xa[j][2 * k2 + 1], b1[j]);
        }
    }
    int e0 = t, e1 = t + 256;
#pragma unroll
    for (int j = 0; j < 4; ++j) {
        unsigned short* co = cb16 + ((size_t)b * NFRAMES + f0 + j) * 512;
        co[(e0 & 3) * 128 + (e0 >> 2)] = f2bf(ftanh(a0[j] + a1[j]));
        co[(e1 & 3) * 128 + (e1 >> 2)] = f2bf(ftanh(b0[j] + b1[j]));
    }
}

__global__ __launch_bounds__(256) void fargan_conv(
    const void* feats, const void* gfeat,
    const int* flag, const unsigned int* wct, unsigned short* cb16)
{
    if (*flag) conv_body<true>(feats, gfeat, wct, cb16);
    else       conv_body<false>(feats, gfeat, wct, cb16);
}

// ---------- kernel 2: sequential recurrence ----------
// Producer/consumer wave specialization: 8 waves (2/SIMD).
//   waves 0-3  (consumer): n-slice finish MFMAs + all elementwise + staging.
//   waves 4-7  (producer): lookback gather, FW/GRU partial K-segments, all SD
//                          MFMAs, feat2s shuffle. Partials handed over through
//                          f32 LDS buffers one barrier ahead of consumption.
// 12 lgkm-only barriers per subframe step, matched in both branches.

__global__ __launch_bounds__(512, 2) void fargan_seq(
    const void* __restrict__ feats, const void* __restrict__ prev_in,
    const int* __restrict__ flag, const unsigned short* __restrict__ cb16,
    const uint4* __restrict__ wbuf, void* __restrict__ outp)
{
    const int t = threadIdx.x;
    const int b0 = blockIdx.x * RPW;
    const int f32 = *flag;

    // ---- LDS (~155 KB) ----
    __shared__ __align__(16) unsigned short hist[RPW * 520];   // bf16 ring, mod-512
    __shared__ __align__(16) unsigned short catb[RPW * 424];   // [feat2s|ps|look|sfw|pad]
    __shared__ __align__(16) unsigned short xg  [RPW * 200];   // [in0|ps|s]
    __shared__ __align__(16) unsigned short skx [RPW * 328];   // [o1|o2|o3|fw|ps]
    __shared__ __align__(16) unsigned short sdbb[RPW * 136];
    __shared__ __align__(16) unsigned short sobb[RPW * 136];
    __shared__ __align__(16) unsigned short v64 [RPW * 72];
    __shared__ __align__(16) unsigned short wsd[128 * 328];    // Wsd, 164u stride
    __shared__ __align__(16) float pcFW[4][64][4];             // FW partial (P->C)
    __shared__ __align__(16) float pcG [4][64][3][4];          // GRU partials r,z,h
    __shared__ int period_s[RPW];

    // ---- Wsd -> LDS from wbuf (512 threads) ----
    for (int fi = t; fi < 8 * 10 * 64; fi += 512) {
        int lane2 = fi & 63, tkb = fi >> 6;
        int kb = tkb % 10, tile = tkb / 10;
        int lq2 = lane2 >> 4, ln2 = lane2 & 15;
        int row = tile * 16 + ln2;
        uint4 v = wbuf[OFF_SD + fi];
        *(uint4*)((unsigned int*)wsd + row * 164 + kb * 16 + lq2 * 4) = v;
    }

    // ---- zero init LDS state + hist fill ----
    for (int i = t; i < RPW * 424; i += 512) catb[i] = 0;
    for (int i = t; i < RPW * 200; i += 512) xg[i] = 0;
    for (int i = t; i < RPW * 328; i += 512) skx[i] = 0;
    for (int i = t; i < RPW * 136; i += 512) { sdbb[i] = 0; sobb[i] = 0; }
    for (int i = t; i < RPW * 72;  i += 512) v64[i] = 0;
    for (int i = t; i < RPW * 512; i += 512) {
        int row = i >> 9, c = i & 511;
        hist[row * 520 + c] = f2bf(ld1f(f32, prev_in, (size_t)(b0 + row) * LPREV + c));
    }
    __syncthreads();
    // initial prev_sub slots (step 0): window[448..511] of prev_in
    for (int i = t; i < RPW * 64; i += 512) {
        int row = i >> 6, c = i & 63;
        unsigned short hh = hist[row * 520 + 448 + c];
        catb[row * 424 + 128 + c] = hh;
        skx [row * 328 + 256 + c] = hh;
        xg  [row * 200 + 64  + c] = hh;
    }

    // producer staging mapping (threads 256..511: 16 threads/row, 8 bf16 each)
    const int prow = (t & 255) >> 4, px16 = t & 15, pe8 = (t & 15) * 8;
    uint4 pfc = {0, 0, 0, 0};
    float pper = 0.f;
    if (t >= 256) {
        // feat2s(step 0) synchronous write; prefetch feat2s(step 1)
        uint4 u0 = *(const uint4*)(cb16 + ((size_t)(b0 + prow) * NFRAMES + 0) * 512 + 0 * 128 + pe8);
        *(uint4*)((unsigned int*)catb + prow * 212 + (pe8 >> 1)) = u0;
        pfc = *(const uint4*)(cb16 + ((size_t)(b0 + prow) * NFRAMES + 0) * 512 + 1 * 128 + pe8);
        if (t < 256 + RPW) {
            pper = ld1f(f32, feats, (size_t)(b0 + (t - 256)) * (NF * NFRAMES) + (NF - 1) * NFRAMES + 0);
            period_s[t - 256] = (int)rintf(pper);
        }
    }
    __syncthreads();

    const floatx4 z4 = {0.f, 0.f, 0.f, 0.f};

    if (t < 256) {
        // ======================= CONSUMER (waves 0-3) =======================
        const int lane = t & 63, w = t >> 6;
        const int lq = lane >> 4, ln = lane & 15;
        const int nj = 16 * w + ln;
        const int n0 = 32 * w + ln, n1 = n0 + 16;

        // resident B-frags
        short8 BfwC[3], Bfwg[2], Bout[4];
        short8 BrC[3][2], BzC[3][2], BiC[3][4], Bg[3][2];
        short8 Bsg[2][4];
#pragma unroll
        for (int j = 0; j < 3; ++j) BfwC[j] = ldB(wbuf, OFF_FW + (w * 13 + 6 + j) * 64 + lane);
#pragma unroll
        for (int kb = 0; kb < 2; ++kb) Bfwg[kb] = ldB(wbuf, OFF_FWG + (w * 2 + kb) * 64 + lane);
#pragma unroll
        for (int G = 0; G < 3; ++G) {
            const int OR = OFF_GRU(G), OZ = OR + 1536, OI = OR + 3072;
#pragma unroll
            for (int kb = 0; kb < 2; ++kb) {
                BrC[G][kb] = ldB(wbuf, OR + (w * 6 + kb) * 64 + lane);
                BzC[G][kb] = ldB(wbuf, OZ + (w * 6 + kb) * 64 + lane);
                Bg[G][kb]  = ldB(wbuf, OFF_WG(G) + (w * 2 + kb) * 64 + lane);
            }
#pragma unroll
            for (int kb = 0; kb < 4; ++kb) BiC[G][kb] = ldB(wbuf, OI + (w * 4 + kb) * 64 + lane);
        }
#pragma unroll
        for (int tile = 0; tile < 2; ++tile)
#pragma unroll
            for (int kb = 0; kb < 4; ++kb)
                Bsg[tile][kb] = ldB(wbuf, OFF_SG + ((2 * w + tile) * 4 + kb) * 64 + lane);
#pragma unroll
        for (int kb = 0; kb < 4; ++kb) Bout[kb] = ldB(wbuf, OFF_OUT + (w * 4 + kb) * 64 + lane);

        floatx4 svr[3];
#pragma unroll
        for (int G = 0; G < 3; ++G) svr[G] = z4;

        int base = 0;
        for (int f = 0; f < NFRAMES; ++f) {
            for (int kk = 0; kk < NSUB; ++kk) {
                // A: producer gathers + FW partials
                barx();
                // B: FW finish (kb6-8) + partial add + tanh -> v64
                {
                    floatx4 C0 = z4, C1 = z4, C2 = z4;
                    C0 = mf(ldA(catb, 212, ln, 6, lq), BfwC[0], C0);
                    C1 = mf(ldA(catb, 212, ln, 7, lq), BfwC[1], C1);
                    C2 = mf(ldA(catb, 212, ln, 8, lq), BfwC[2], C2);
                    floatx4 pf = *(const floatx4*)&pcFW[w][lane][0];
#pragma unroll
                    for (int r = 0; r < 4; ++r) {
                        int m = 4 * lq + r;
                        v64[m * 72 + nj] = f2bf(ftanh((C0[r] + C1[r]) + (C2[r] + pf[r])));
                    }
                }
                barx();
                // C: FWG glu -> fw
                {
                    floatx4 C = z4;
#pragma unroll
                    for (int kb = 0; kb < 2; ++kb)
                        C = mf(ldA(v64, 36, ln, kb, lq), Bfwg[kb], C);
#pragma unroll
                    for (int r = 0; r < 4; ++r) {
                        int m = 4 * lq + r;
                        float vp = bf2f(v64[m * 72 + nj]);
                        unsigned short ob = f2bf(vp * fsig(C[r]));
                        skx[m * 328 + 192 + nj] = ob;   // fw slot
                        xg [m * 200 + nj]       = ob;   // in0 for GRU1
                    }
                }
                barx();
                // GRU finish + GLU x3
#pragma unroll
                for (int G = 0; G < 3; ++G) {
                    {
                        floatx4 Cr = z4, Cz = z4, Ci = z4;
                        {
                            short8 a = ldA(xg, 100, ln, 0, lq);
                            Cr = mf(a, BrC[G][0], Cr);
                            Cz = mf(a, BzC[G][0], Cz);
                            Ci = mf(a, BiC[G][0], Ci);
                        }
                        {
                            short8 a = ldA(xg, 100, ln, 1, lq);
                            Cr = mf(a, BrC[G][1], Cr);
                            Cz = mf(a, BzC[G][1], Cz);
                            Ci = mf(a, BiC[G][1], Ci);
                        }
                        Ci = mf(ldA(xg, 100, ln, 2, lq), BiC[G][2], Ci);
                        Ci = mf(ldA(xg, 100, ln, 3, lq), BiC[G][3], Ci);
                        floatx4 pr = *(const floatx4*)&pcG[w][lane][0][0];
                        floatx4 pz = *(const floatx4*)&pcG[w][lane][1][0];
                        floatx4 ph = *(const floatx4*)&pcG[w][lane][2][0];
#pragma unroll
                        for (int r = 0; r < 4; ++r) {
                            int m = 4 * lq + r;
                            float rr = fsig(Cr[r] + pr[r]);
                            float zz = fsig(Cz[r] + pz[r]);
                            float nn = ftanh(Ci[r] + rr * ph[r]);
                            float sn = fmaf(zz, svr[G][r] - nn, nn);
                            svr[G][r] = sn;
                            v64[m * 72 + nj] = f2bf(sn);
                            if (G < 2) xg[m * 200 + 128 + nj] = f2bf(svr[G + 1][r]);
                        }
                    }
                    barx();                            // D/F/H
                    {
                        floatx4 C = z4;
#pragma unroll
                        for (int kb = 0; kb < 2; ++kb)
                            C = mf(ldA(v64, 36, ln, kb, lq), Bg[G][kb], C);
#pragma unroll
                        for (int r = 0; r < 4; ++r) {
                            int m = 4 * lq + r;
                            unsigned short ob = f2bf(svr[G][r] * fsig(C[r]));
                            skx[m * 328 + G * 64 + nj] = ob;
                            if (G < 2) xg[m * 200 + nj] = ob;
                        }
                    }
                    barx();                            // E/G/I
                }
                // J: producer finishes SD
                barx();
                // K: SG (glu), both tiles
                {
                    floatx4 Ca = z4, Cb = z4, Cc = z4, Cd = z4;
#pragma unroll
                    for (int kb = 0; kb < 4; ++kb) {
                        short8 a = ldA(sdbb, 68, ln, kb, lq);
                        if (kb & 1) { Cb = mf(a, Bsg[0][kb], Cb); Cd = mf(a, Bsg[1][kb], Cd); }
                        else        { Ca = mf(a, Bsg[0][kb], Ca); Cc = mf(a, Bsg[1][kb], Cc); }
                    }
#pragma unroll
                    for (int r = 0; r < 4; ++r) {
                        int m = 4 * lq + r;
                        float s0 = bf2f(sdbb[m * 136 + n0]);
                        float s1 = bf2f(sdbb[m * 136 + n1]);
                        sobb[m * 136 + n0] = f2bf(s0 * fsig(Ca[r] + Cb[r]));
                        sobb[m * 136 + n1] = f2bf(s1 * fsig(Cc[r] + Cd[r]));
                    }
                }
                barx();
                // L: OUT (tanh) + state staging + global store
                {
                    floatx4 Ca = z4, Cb = z4;
#pragma unroll
                    for (int kb = 0; kb < 4; ++kb) {
                        short8 a = ldA(sobb, 68, ln, kb, lq);
                        if (kb & 1) Cb = mf(a, Bout[kb], Cb);
                        else        Ca = mf(a, Bout[kb], Ca);
                    }
#pragma unroll
                    for (int r = 0; r < 4; ++r) {
                        int m = 4 * lq + r;
                        float ov = ftanh(Ca[r] + Cb[r]);
                        unsigned short ob = f2bf(ov);
                        hist[m * 520 + ((base + nj) & 511)] = ob;
                        catb[m * 424 + 128 + nj] = ob;              // ps for FW
                        skx [m * 328 + 256 + nj] = ob;              // ps for SD
                        xg  [m * 200 + 64  + nj] = ob;              // ps for GRUs
                        xg  [m * 200 + 128 + nj] = f2bf(svr[0][r]); // s1 for GRU1 partials
                        size_t oi = (size_t)(b0 + m) * (NFRAMES * NSUB * SS)
                                  + f * (NSUB * SS) + kk * SS + nj;
                        if (f32) ((float*)outp)[oi] = ov;
                        else     ((unsigned short*)outp)[oi] = ob;
                    }
                }
                barx();
                base += SS;
            }
        }
    } else {
        // ======================= PRODUCER (waves 4-7) =======================
        const int lane = t & 63, w4 = (t >> 6) - 4;
        const int lq = lane >> 4, ln = lane & 15;
        const int n0 = 32 * w4 + ln, n1 = n0 + 16;

        // resident B-frags: FW kb{0-5,9-12}; GRU r,z kb2-5; h kb4,5
        short8 BfwP[10];
        short8 BrP[3][4], BzP[3][4], BhP[3][2];
        const int fwkb[10] = {0, 1, 2, 3, 4, 5, 9, 10, 11, 12};
#pragma unroll
        for (int j = 0; j < 10; ++j)
            BfwP[j] = ldB(wbuf, OFF_FW + (w4 * 13 + fwkb[j]) * 64 + lane);
#pragma unroll
        for (int G = 0; G < 3; ++G) {
            const int OR = OFF_GRU(G), OZ = OR + 1536, OH = OR + 4096;
#pragma unroll
            for (int j = 0; j < 4; ++j) {
                BrP[G][j] = ldB(wbuf, OR + (w4 * 6 + 2 + j) * 64 + lane);
                BzP[G][j] = ldB(wbuf, OZ + (w4 * 6 + 2 + j) * 64 + lane);
            }
#pragma unroll
            for (int j = 0; j < 2; ++j)
                BhP[G][j] = ldB(wbuf, OH + (w4 * 2 + j) * 64 + lane);
        }

        int base = 0;
        for (int f = 0; f < NFRAMES; ++f) {
            for (int kk = 0; kk < NSUB; ++kk) {
                floatx4 SD00 = z4, SD01 = z4, SD10 = z4, SD11 = z4;

                // SD 2-kb segment on this wave's two n-tiles
                auto sdseg = [&](int kbs) {
                    {
                        int kb = kbs;
                        short8 a = ldA(skx, 164, ln, kb, lq);
                        SD00 = mf(a, ldA(wsd, 164, n0, kb, lq), SD00);
                        SD10 = mf(a, ldA(wsd, 164, n1, kb, lq), SD10);
                    }
                    {
                        int kb = kbs + 1;
                        short8 a = ldA(skx, 164, ln, kb, lq);
                        SD01 = mf(a, ldA(wsd, 164, n0, kb, lq), SD01);
                        SD11 = mf(a, ldA(wsd, 164, n1, kb, lq), SD11);
                    }
                };
                // GRU partials kb2-5 (ps + s) -> pcG
                auto grupart = [&](int G) {
                    floatx4 Cr = z4, Cz = z4, Ch = z4;
                    {
                        short8 a = ldA(xg, 100, ln, 2, lq);
                        Cr = mf(a, BrP[G][0], Cr); Cz = mf(a, BzP[G][0], Cz);
                    }
                    {
                        short8 a = ldA(xg, 100, ln, 3, lq);
                        Cr = mf(a, BrP[G][1], Cr); Cz = mf(a, BzP[G][1], Cz);
                    }
                    {
                        short8 a = ldA(xg, 100, ln, 4, lq);
                        Cr = mf(a, BrP[G][2], Cr); Cz = mf(a, BzP[G][2], Cz);
                        Ch = mf(a, BhP[G][0], Ch);
                    }
                    {
                        short8 a = ldA(xg, 100, ln, 5, lq);
                        Cr = mf(a, BrP[G][3], Cr); Cz = mf(a, BzP[G][3], Cz);
                        Ch = mf(a, BhP[G][1], Ch);
                    }
                    *(floatx4*)&pcG[w4][lane][0][0] = Cr;
                    *(floatx4*)&pcG[w4][lane][1][0] = Cz;
                    *(floatx4*)&pcG[w4][lane][2][0] = Ch;
                };

                // ====== A: lookback gather + FW partials -> pcFW ======
                {
                    int per = period_s[prow];
#pragma unroll
                    for (int ii = 0; ii < 5; ++ii) {
                        int i = px16 * 5 + ii;
                        if (i < 68) {
                            int idx = LPREV - per + i - 2;
                            if (idx >= LPREV) idx -= per;
                            catb[prow * 424 + 192 + i] = hist[prow * 520 + ((base + idx) & 511)];
                        }
                    }
                    floatx4 C0 = z4, C1 = z4, C2 = z4, C3 = z4;
                    C0 = mf(ldA(catb, 212, ln,  0, lq), BfwP[0], C0);
                    C1 = mf(ldA(catb, 212, ln,  1, lq), BfwP[1], C1);
                    C2 = mf(ldA(catb, 212, ln,  2, lq), BfwP[2], C2);
                    C3 = mf(ldA(catb, 212, ln,  3, lq), BfwP[3], C3);
                    C0 = mf(ldA(catb, 212, ln,  4, lq), BfwP[4], C0);
                    C1 = mf(ldA(catb, 212, ln,  5, lq), BfwP[5], C1);
                    C2 = mf(ldA(catb, 212, ln,  9, lq), BfwP[6], C2);
                    C3 = mf(ldA(catb, 212, ln, 10, lq), BfwP[7], C3);
                    C0 = mf(ldA(catb, 212, ln, 11, lq), BfwP[8], C0);
                    C1 = mf(ldA(catb, 212, ln, 12, lq), BfwP[9], C1);
                    floatx4 s = (C0 + C1) + (C2 + C3);
                    *(floatx4*)&pcFW[w4][lane][0] = s;
                }
                barx();                                    // A
                // ====== B: GRU1 partials ======
                grupart(0);
                barx();                                    // B
                // ====== C: idle ======
                barx();                                    // C
                // ====== D: SD fw segment (kb6,7) ======
                sdseg(6);
                barx();                                    // D
                // ====== E: GRU2 partials ======
                grupart(1);
                barx();                                    // E
                // ====== F: SD o1 (kb0,1) + ps (kb8,9) ======
                sdseg(0);
                sdseg(8);
                barx();                                    // F
                // ====== G: GRU3 partials ======
                grupart(2);
                barx();                                    // G
                // ====== H: SD o2 (kb2,3) ======
                sdseg(2);
                barx();                                    // H
                // ====== I: idle ======
                barx();                                    // I
                // ====== J: SD o3 (kb4,5) + tanh -> sdbb ======
                {
                    sdseg(4);
#pragma unroll
                    for (int r = 0; r < 4; ++r) {
                        int m = 4 * lq + r;
                        sdbb[m * 136 + n0] = f2bf(ftanh(SD00[r] + SD01[r]));
                        sdbb[m * 136 + n1] = f2bf(ftanh(SD10[r] + SD11[r]));
                    }
                }
                barx();                                    // J
                // ====== K: idle (consumer does SG) ======
                barx();                                    // K
                // ====== L: feat2s shuffle + prefetch + period ======
                {
                    unsigned int* cat32 = (unsigned int*)catb;
                    int cb = prow * 212;
                    int u0 = pe8 >> 1;
                    unsigned int o0 = cat32[cb + u0 + 0];
                    unsigned int o1 = cat32[cb + u0 + 1];
                    unsigned int o2 = cat32[cb + u0 + 2];
                    unsigned int o3 = cat32[cb + u0 + 3];
                    cat32[cb + 130 + u0 + 0] = o0;
                    cat32[cb + 130 + u0 + 1] = o1;
                    cat32[cb + 130 + u0 + 2] = o2;
                    cat32[cb + 130 + u0 + 3] = o3;
                    *(uint4*)(cat32 + cb + u0) = pfc;
                    int sN = f * 4 + kk + 2;
                    if (sN > NFRAMES * 4 - 1) sN = NFRAMES * 4 - 1;
                    pfc = *(const uint4*)(cb16
                        + ((size_t)(b0 + prow) * NFRAMES + (sN >> 2)) * 512 + (sN & 3) * 128 + pe8);
                    if (kk == 0 && t < 256 + RPW) {
                        int fN = (f + 1 < NFRAMES) ? f + 1 : f;
                        pper = ld1f(f32, feats,
                                    (size_t)(b0 + (t - 256)) * (NF * NFRAMES) + (NF - 1) * NFRAMES + fN);
                    }
                    if (kk == 3 && t < 256 + RPW) period_s[t - 256] = (int)rintf(pper);
                }
                barx();                                    // L
                base += SS;
            }
        }
    }
}

// ---------- launch ----------
extern "C" void kernel_launch(void* const* d_in, const int* in_sizes, int n_in,
                              void* d_out, int out_size, void* d_ws, size_t ws_size,
                              hipStream_t stream) {
    const void* feats = d_in[0];
    const void* gfeat = d_in[1];
    const void* prev  = d_in[2];
    const void* Wc1   = d_in[3];
    const void* Wc2   = d_in[4];
    const void* Wc3   = d_in[5];
    const void* Wfw   = d_in[6];
    const void* Wfwg  = d_in[7];
    const void* Wih1  = d_in[8];
    const void* Whh1  = d_in[9];
    const void* Wih2  = d_in[10];
    const void* Whh2  = d_in[11];
    const void* Wih3  = d_in[12];
    const void* Whh3  = d_in[13];
    const void* Wg1   = d_in[14];
    const void* Wg2   = d_in[15];
    const void* Wg3   = d_in[16];
    const void* Wsg   = d_in[17];
    const void* Wsd   = d_in[18];
    const void* Wout  = d_in[19];

    int*            flag = (int*)d_ws;                                      // @0
    unsigned short* cb16 = (unsigned short*)((char*)d_ws + 256);            // 6,553,600 B
    unsigned int*   wct  = (unsigned int*)((char*)d_ws + 256 + 6553600);    // 524,288 B
    uint4*          wbuf = (uint4*)((char*)d_ws + 256 + 6553600 + 524288);  // 438,272 B

    fargan_detect<<<1, 1, 0, stream>>>(feats, flag);
    fargan_prep<<<(NFRAG + 255) / 256, 256, 0, stream>>>(flag, Wfw, Wfwg,
        Wih1, Whh1, Wih2, Whh2, Wih3, Whh3, Wg1, Wg2, Wg3, Wsg, Wsd, Wout, wbuf);
    fargan_prep_conv<<<512, 256, 0, stream>>>(flag, Wc1, Wc2, Wc3, wct);
    fargan_conv<<<BATCH * 25, 256, 0, stream>>>(feats, gfeat, flag, wct, cb16);
    fargan_seq<<<BATCH / RPW, 512, 0, stream>>>(feats, prev, flag, cb16, wbuf, d_out);
}

// Round 3
// 1946.033 us; speedup vs baseline: 1.3467x; 1.1266x over previous
//
#include <hip/hip_runtime.h>
#include <hip/hip_bf16.h>

// FARGAN vocoder on MI355X. Sizes fixed by the reference:
#define SS      64
#define NSUB    4
#define LPREV   512
#define NF      193
#define NFRAMES 100
#define BATCH   64
#define RPW     16     // batch rows per workgroup (MFMA M)
#define HSTR    514    // hist row stride (u16); 257 u32 -> odd bank stagger

typedef __attribute__((ext_vector_type(8))) short   short8;   // 8 bf16 (4 VGPRs)
typedef __attribute__((ext_vector_type(4))) float   floatx4;  // MFMA C/D

// ---------- scalar helpers ----------
__device__ __forceinline__ float bf2f(unsigned short u) {
    return __uint_as_float(((unsigned int)u) << 16);
}
__device__ __forceinline__ unsigned short f2bf(float x) {
    unsigned int u = __float_as_uint(x);
    return (unsigned short)((u + 0x7fffu + ((u >> 16) & 1u)) >> 16);
}
__device__ __forceinline__ unsigned int packbf(float a, float b) {
    return (unsigned int)f2bf(a) | ((unsigned int)f2bf(b) << 16);
}
__device__ __forceinline__ float fexp2(float x) {
#if __has_builtin(__builtin_amdgcn_exp2f)
    return __builtin_amdgcn_exp2f(x);
#else
    return exp2f(x);
#endif
}
__device__ __forceinline__ float frcp(float x) {
#if __has_builtin(__builtin_amdgcn_rcpf)
    return __builtin_amdgcn_rcpf(x);
#else
    return 1.0f / x;
#endif
}
__device__ __forceinline__ float fsig(float x) {
    return frcp(1.0f + fexp2(-1.442695041f * x));
}
__device__ __forceinline__ float ftanh(float x) {
    return fmaf(2.0f, frcp(1.0f + fexp2(-2.885390082f * x)), -1.0f);
}
__device__ __forceinline__ float ld1f(int f32, const void* p, size_t i) {
    if (f32) return ((const float*)p)[i];
    return bf2f(((const unsigned short*)p)[i]);
}
__device__ __forceinline__ float lo16(unsigned int u) { return __uint_as_float(u << 16); }
__device__ __forceinline__ float hi16(unsigned int u) { return __uint_as_float(u & 0xffff0000u); }

// packed f32->bf16 RNE conversion (1 instr / 2 values)
__device__ __forceinline__ unsigned int cvtpk(float lo, float hi) {
    unsigned int r;
    asm("v_cvt_pk_bf16_f32 %0, %1, %2" : "=v"(r) : "v"(lo), "v"(hi));
    return r;
}
// store 4 values down a column (rows 4lq..4lq+3): 2 cvt_pk + 2 shifts + 4 b16 stores
__device__ __forceinline__ void st4c(unsigned short* p, int strideU16,
                                     float a, float b, float c, float d) {
    unsigned int p01 = cvtpk(a, b), p23 = cvtpk(c, d);
    p[0]             = (unsigned short)p01;
    p[strideU16]     = (unsigned short)(p01 >> 16);
    p[2 * strideU16] = (unsigned short)p23;
    p[3 * strideU16] = (unsigned short)(p23 >> 16);
}

// MFMA wrapper
__device__ __forceinline__ floatx4 mf(short8 a, short8 b, floatx4 c) {
    return __builtin_amdgcn_mfma_f32_16x16x32_bf16(a, b, c, 0, 0, 0);
}

// A-fragment from packed-bf16 LDS buffer: row m, k-block kb, quad q. strideU in u32.
__device__ __forceinline__ short8 ldA(const unsigned short* buf, int strideU,
                                      int m, int kb, int q) {
    const unsigned int* p = (const unsigned int*)buf + m * strideU + kb * 16 + q * 4;
    uint4 u = *(const uint4*)p;
    return __builtin_bit_cast(short8, u);
}
// B-fragment from prepacked weight buffer
__device__ __forceinline__ short8 ldB(const uint4* __restrict__ w, int idx) {
    return __builtin_bit_cast(short8, w[idx]);
}

// lgkm-only barrier: do NOT drain vmcnt (prefetch loads + output stores stay
// in flight). Memory clobbers keep the compiler from moving LDS ops across.
__device__ __forceinline__ void barx() {
    asm volatile("s_waitcnt lgkmcnt(0)" ::: "memory");
    __builtin_amdgcn_s_barrier();
    asm volatile("" ::: "memory");
}

// ---------- wbuf layout (units = 16B frags) ----------
#define OFF_FW   0        // 4t x 13kb
#define OFF_FWG  3328     // 4t x 2kb
#define OFF_GRU(G) (3840 + 4608*(G))   // r@+0(6kb) z@+1536(6kb) i@+3072(4kb) h@+4096(2kb)
#define OFF_WG(G)  (17664 + 512*(G))   // 4t x 2kb
#define OFF_SD   19200    // 8t x 10kb
#define OFF_SG   24320    // 8t x 4kb
#define OFF_OUT  26368    // 4t x 4kb
#define NFRAG    27392

// ---------- dtype detector ----------
__global__ void fargan_detect(const void* feats, int* flag) {
    const float* pf = (const float*)feats;
    int ok = 1;
    for (int f = 0; f < 50; ++f) {
        float v = pf[192 * NFRAMES + f];
        if (!(v >= 63.0f && v <= 301.0f)) { ok = 0; break; }
    }
    *flag = ok;
}

// ---------- weight prep: repack all seq weights into frag order ----------
__global__ __launch_bounds__(256) void fargan_prep(
    const int* __restrict__ flag,
    const void* Wfw, const void* Wfwg,
    const void* Wih1, const void* Whh1, const void* Wih2, const void* Whh2,
    const void* Wih3, const void* Whh3,
    const void* Wg1, const void* Wg2, const void* Wg3,
    const void* Wsg, const void* Wsd, const void* Wout,
    uint4* __restrict__ wbuf)
{
    int fi = blockIdx.x * 256 + threadIdx.x;
    if (fi >= NFRAG) return;
    int f32 = *flag;
    const void* mats[14] = {Wfw, Wfwg, Wih1, Whh1, Wih2, Whh2, Wih3, Whh3,
                            Wg1, Wg2, Wg3, Wsg, Wsd, Wout};
    const int NSEG = 20;
    const int sb[NSEG]  = {0,3328, 3840,5376,6912,7936, 8448,9984,11520,12544,
                           13056,14592,16128,17152, 17664,18176,18688, 19200,24320,26368};
    const int sa[NSEG]  = {0,1, 2,2,2,3, 4,4,4,5, 6,6,6,7, 8,9,10, 12,11,13};
    const int sbx[NSEG] = {-1,-1, 3,3,-1,-1, 5,5,-1,-1, 7,7,-1,-1, -1,-1,-1, -1,-1,-1};
    const int sro[NSEG] = {0,0, 0,64,128,128, 0,64,128,128, 0,64,128,128, 0,0,0, 0,0,0};
    const int skb[NSEG] = {13,2, 6,6,4,2, 6,6,4,2, 6,6,4,2, 2,2,2, 10,4,4};
    const int ska[NSEG] = {388,64, 128,128,128,64, 128,128,128,64, 128,128,128,64,
                           64,64,64, 320,128,128};
    const int skr[NSEG] = {388,64, 192,192,128,64, 192,192,128,64, 192,192,128,64,
                           64,64,64, 320,128,128};
    int s = 0;
    for (int i = 1; i < NSEG; ++i) if (fi >= sb[i]) s = i;
    int local = fi - sb[s];
    int ln = local & 15, lq = (local >> 4) & 3, tkb = local >> 6;
    int KB = skb[s];
    int kb = tkb % KB, tile = tkb / KB;
    int row = sro[s] + tile * 16 + ln;
    int Ka = ska[s], Kr = skr[s];
    union { unsigned short h[8]; uint4 v; } u;
#pragma unroll
    for (int j = 0; j < 8; ++j) {
        int k = kb * 32 + lq * 8 + j;
        unsigned short val = 0;
        if (k < Kr) {
            const void* m; size_t off;
            if (sbx[s] >= 0 && k >= Ka) { m = mats[sbx[s]]; off = (size_t)row * 64 + (k - Ka); }
            else                        { m = mats[sa[s]];  off = (size_t)row * Ka + k; }
            val = f32 ? f2bf(((const float*)m)[off]) : ((const unsigned short*)m)[off];
        }
        u.h[j] = val;
    }
    wbuf[fi] = u.v;
}

// ---------- prep: repack Wc1/2/3 transposed + bf16-pair packed ----------
__global__ __launch_bounds__(256) void fargan_prep_conv(
    const int* __restrict__ flag,
    const void* Wc1, const void* Wc2, const void* Wc3,
    unsigned int* __restrict__ wct)
{
    int idx = blockIdx.x * 256 + threadIdx.x;
    if (idx >= 131072) return;
    int f32 = *flag;
    const void* W; int n, k2;
    if (idx < 32768)      { W = Wc1; k2 = idx >> 8, n = idx & 255; }
    else if (idx < 65536) { W = Wc2; k2 = (idx - 32768) >> 8; n = idx & 255; }
    else                  { W = Wc3; k2 = (idx - 65536) >> 9; n = (idx - 65536) & 511; }
    size_t off = (size_t)n * 256 + 2 * k2;
    unsigned int v;
    if (f32) {
        const float* p = (const float*)W + off;
        v = packbf(p[0], p[1]);
    } else {
        v = *(const unsigned int*)((const unsigned short*)W + off);
    }
    wct[idx] = v;
}

// ---------- kernel 1: frame conv -> bf16 output cb16[b][f][k*128+j] ----------
template<bool F32>
__device__ __forceinline__ void conv_body(
    const void* __restrict__ feats, const void* __restrict__ gfeat,
    const unsigned int* __restrict__ wct, unsigned short* __restrict__ cb16)
{
    int blk = blockIdx.x;
    int b = blk / 25, fq = blk - b * 25;
    int f0 = fq * 4;
    int t = threadIdx.x;
    __shared__ float xa[4][256], xb[4][256];

#pragma unroll
    for (int j = 0; j < 4; ++j) {
        float v;
        if (t < 192) v = ld1f(F32 ? 1 : 0, feats, (size_t)b * (NF * NFRAMES) + t * NFRAMES + f0 + j);
        else         v = ld1f(F32 ? 1 : 0, gfeat, (size_t)b * 64 + (t - 192));
        xa[j][t] = v;
    }
    __syncthreads();

    const unsigned int* w1 = wct;
    const unsigned int* w2 = wct + 32768;
    const unsigned int* w3 = wct + 65536;

    float a0[4], a1[4], b0[4], b1[4];
#pragma unroll
    for (int j = 0; j < 4; ++j) { a0[j] = 0.f; a1[j] = 0.f; }
#pragma unroll 4
    for (int k2 = 0; k2 < 128; ++k2) {
        unsigned int u = w1[k2 * 256 + t];
        float lo = lo16(u), hi = hi16(u);
#pragma unroll
        for (int j = 0; j < 4; ++j) {
            a0[j] = fmaf(lo, xa[j][2 * k2], a0[j]);
            a1[j] = fmaf(hi, xa[j][2 * k2 + 1], a1[j]);
        }
    }
#pragma unroll
    for (int j = 0; j < 4; ++j) xb[j][t] = ftanh(a0[j] + a1[j]);
    __syncthreads();

#pragma unroll
    for (int j = 0; j < 4; ++j) { a0[j] = 0.f; a1[j] = 0.f; }
#pragma unroll 4
    for (int k2 = 0; k2 < 128; ++k2) {
        unsigned int u = w2[k2 * 256 + t];
        float lo = lo16(u), hi = hi16(u);
#pragma unroll
        for (int j = 0; j < 4; ++j) {
            a0[j] = fmaf(lo, xb[j][2 * k2], a0[j]);
            a1[j] = fmaf(hi, xb[j][2 * k2 + 1], a1[j]);
        }
    }
    __syncthreads();
#pragma unroll
    for (int j = 0; j < 4; ++j) xa[j][t] = ftanh(a0[j] + a1[j]);
    __syncthreads();

#pragma unroll
    for (int j = 0; j < 4; ++j) { a0[j] = 0.f; a1[j] = 0.f; b0[j] = 0.f; b1[j] = 0.f; }
#pragma unroll 4
    for (int k2 = 0; k2 < 128; ++k2) {
        unsigned int u  = w3[k2 * 512 + t];
        unsigned int u2 = w3[k2 * 512 + t + 256];
        float lo = lo16(u), hi = hi16(u), lo2 = lo16(u2), hi2 = hi16(u2);
#pragma unroll
        for (int j = 0; j < 4; ++j) {
            a0[j] = fmaf(lo,  xa[j][2 * k2],     a0[j]);
            a1[j] = fmaf(hi,  xa[j][2 * k2 + 1], a1[j]);
            b0[j] = fmaf(lo2, xa[j][2 * k2],     b0[j]);
            b1[j] = fmaf(hi2, xa[j][2 * k2 + 1], b1[j]);
        }
    }
    int e0 = t, e1 = t + 256;
#pragma unroll
    for (int j = 0; j < 4; ++j) {
        unsigned short* co = cb16 + ((size_t)b * NFRAMES + f0 + j) * 512;
        co[(e0 & 3) * 128 + (e0 >> 2)] = f2bf(ftanh(a0[j] + a1[j]));
        co[(e1 & 3) * 128 + (e1 >> 2)] = f2bf(ftanh(b0[j] + b1[j]));
    }
}

__global__ __launch_bounds__(256) void fargan_conv(
    const void* feats, const void* gfeat,
    const int* flag, const unsigned int* wct, unsigned short* cb16)
{
    if (*flag) conv_body<true>(feats, gfeat, wct, cb16);
    else       conv_body<false>(feats, gfeat, wct, cb16);
}

// ---------- kernel 2: sequential recurrence ----------
// Producer/consumer wave specialization, 8 waves (2/SIMD), 256-VGPR budget.
// Unified buffers: ps written once (psb), GLU outputs once (skx), states in
// sgb; all kb-aligned so every matmul reads its region directly. Step-constant
// fragments (psb, SD-ps weights) are loaded once and reused; producer's GRU
// partial phases are pure-MFMA (zero ds_reads).

__global__ __launch_bounds__(512) __attribute__((amdgpu_waves_per_eu(2, 2)))
void fargan_seq(
    const void* __restrict__ feats, const void* __restrict__ prev_in,
    const int* __restrict__ flag, const unsigned short* __restrict__ cb16,
    const uint4* __restrict__ wbuf, void* __restrict__ outp)
{
    const int t = threadIdx.x;
    const int b0 = blockIdx.x * RPW;
    const int f32 = *flag;

    // ---- LDS (~151 KB) ----
    __shared__ __align__(16) unsigned short hist[RPW * HSTR];  // bf16 ring, mod-512
    __shared__ __align__(16) unsigned short catb[RPW * 424];   // [feat2s|hole|look|sfw|pad]
    __shared__ __align__(16) unsigned short psb [RPW * 72];    // prev_sub (once)
    __shared__ __align__(16) unsigned short sgb [RPW * 72];    // staged GRU state
    __shared__ __align__(16) unsigned short skx [RPW * 264];   // [o1|o2|o3|fw]
    __shared__ __align__(16) unsigned short sdbb[RPW * 136];
    __shared__ __align__(16) unsigned short sobb[RPW * 136];
    __shared__ __align__(16) unsigned short v64 [RPW * 72];
    __shared__ __align__(16) unsigned short wsd[128 * 328];    // Wsd, 164u stride
    __shared__ __align__(16) float pcFW[4][64][4];             // FW partial (P->C)
    __shared__ __align__(16) float pcG [4][64][3][4];          // GRU partials r,z,h
    __shared__ int period_s[RPW];

    // ---- Wsd -> LDS from wbuf (512 threads) ----
    for (int fi = t; fi < 8 * 10 * 64; fi += 512) {
        int lane2 = fi & 63, tkb = fi >> 6;
        int kb = tkb % 10, tile = tkb / 10;
        int lq2 = lane2 >> 4, ln2 = lane2 & 15;
        int row = tile * 16 + ln2;
        uint4 v = wbuf[OFF_SD + fi];
        *(uint4*)((unsigned int*)wsd + row * 164 + kb * 16 + lq2 * 4) = v;
    }

    // ---- zero init LDS state + hist fill ----
    for (int i = t; i < RPW * 424; i += 512) catb[i] = 0;
    for (int i = t; i < RPW * 72;  i += 512) { psb[i] = 0; sgb[i] = 0; v64[i] = 0; }
    for (int i = t; i < RPW * 264; i += 512) skx[i] = 0;
    for (int i = t; i < RPW * 136; i += 512) { sdbb[i] = 0; sobb[i] = 0; }
    for (int i = t; i < RPW * 512; i += 512) {
        int row = i >> 9, c = i & 511;
        hist[row * HSTR + c] = f2bf(ld1f(f32, prev_in, (size_t)(b0 + row) * LPREV + c));
    }
    __syncthreads();
    // initial prev_sub (step 0): window[448..511] of prev_in -> psb
    for (int i = t; i < RPW * 64; i += 512) {
        int row = i >> 6, c = i & 63;
        psb[row * 72 + c] = hist[row * HSTR + 448 + c];
    }

    // producer staging mapping (threads 256..511: 16 threads/row, 8 bf16 each)
    const int prow = (t & 255) >> 4, px16 = t & 15, pe8 = (t & 15) * 8;
    uint4 pfc = {0, 0, 0, 0};
    float pper = 0.f;
    if (t >= 256) {
        // feat2s(step 0) synchronous write; prefetch feat2s(step 1)
        uint4 u0 = *(const uint4*)(cb16 + ((size_t)(b0 + prow) * NFRAMES + 0) * 512 + 0 * 128 + pe8);
        *(uint4*)((unsigned int*)catb + prow * 212 + (pe8 >> 1)) = u0;
        pfc = *(const uint4*)(cb16 + ((size_t)(b0 + prow) * NFRAMES + 0) * 512 + 1 * 128 + pe8);
        if (t < 256 + RPW) {
            pper = ld1f(f32, feats, (size_t)(b0 + (t - 256)) * (NF * NFRAMES) + (NF - 1) * NFRAMES + 0);
            period_s[t - 256] = (int)rintf(pper);
        }
    }
    __syncthreads();

    const floatx4 z4 = {0.f, 0.f, 0.f, 0.f};

    if (t < 256) {
        // ======================= CONSUMER (waves 0-3) =======================
        const int lane = t & 63, w = t >> 6;
        const int lq = lane >> 4, ln = lane & 15;
        const int nj = 16 * w + ln;
        const int n0 = 32 * w + ln, n1 = n0 + 16;
        const int m0 = 4 * lq;

        // resident B-frags
        short8 BfwC[3], Bfwg[2], Bout[4];
        short8 BrC[3][2], BzC[3][2], BiC[3][4], Bg[3][2];
        short8 Bsg[2][4];
#pragma unroll
        for (int j = 0; j < 3; ++j) BfwC[j] = ldB(wbuf, OFF_FW + (w * 13 + 6 + j) * 64 + lane);
#pragma unroll
        for (int kb = 0; kb < 2; ++kb) Bfwg[kb] = ldB(wbuf, OFF_FWG + (w * 2 + kb) * 64 + lane);
#pragma unroll
        for (int G = 0; G < 3; ++G) {
            const int OR = OFF_GRU(G), OZ = OR + 1536, OI = OR + 3072;
#pragma unroll
            for (int kb = 0; kb < 2; ++kb) {
                BrC[G][kb] = ldB(wbuf, OR + (w * 6 + kb) * 64 + lane);
                BzC[G][kb] = ldB(wbuf, OZ + (w * 6 + kb) * 64 + lane);
                Bg[G][kb]  = ldB(wbuf, OFF_WG(G) + (w * 2 + kb) * 64 + lane);
            }
#pragma unroll
            for (int kb = 0; kb < 4; ++kb) BiC[G][kb] = ldB(wbuf, OI + (w * 4 + kb) * 64 + lane);
        }
#pragma unroll
        for (int tile = 0; tile < 2; ++tile)
#pragma unroll
            for (int kb = 0; kb < 4; ++kb)
                Bsg[tile][kb] = ldB(wbuf, OFF_SG + ((2 * w + tile) * 4 + kb) * 64 + lane);
#pragma unroll
        for (int kb = 0; kb < 4; ++kb) Bout[kb] = ldB(wbuf, OFF_OUT + (w * 4 + kb) * 64 + lane);

        floatx4 svr[3];
#pragma unroll
        for (int G = 0; G < 3; ++G) svr[G] = z4;

        int base = 0;
        for (int f = 0; f < NFRAMES; ++f) {
            for (int kk = 0; kk < NSUB; ++kk) {
                // ====== A: prefetch step-constant ps A-frags (used D/F/H) ======
                short8 cps0 = ldA(psb, 36, ln, 0, lq);
                short8 cps1 = ldA(psb, 36, ln, 1, lq);
                barx();                                    // A
                // ====== B: FW finish (kb6-8) + partial + tanh -> v64 ======
                float xr[4];
                {
                    short8 a6 = ldA(catb, 212, ln, 6, lq);
                    short8 a7 = ldA(catb, 212, ln, 7, lq);
                    short8 a8 = ldA(catb, 212, ln, 8, lq);
                    floatx4 pf = *(const floatx4*)&pcFW[w][lane][0];
                    floatx4 C0 = mf(a6, BfwC[0], z4);
                    floatx4 C1 = mf(a7, BfwC[1], z4);
                    floatx4 C2 = mf(a8, BfwC[2], z4);
#pragma unroll
                    for (int r = 0; r < 4; ++r)
                        xr[r] = ftanh((C0[r] + C1[r]) + (C2[r] + pf[r]));
                    st4c(&v64[m0 * 72 + nj], 72, xr[0], xr[1], xr[2], xr[3]);
                }
                barx();                                    // B
                // ====== C: FWG glu -> skx fw; prefetch pcG (GRU1) ======
                floatx4 pgr, pgz, pgh;
                {
                    short8 a0 = ldA(v64, 36, ln, 0, lq);
                    short8 a1 = ldA(v64, 36, ln, 1, lq);
                    pgr = *(const floatx4*)&pcG[w][lane][0][0];
                    pgz = *(const floatx4*)&pcG[w][lane][1][0];
                    pgh = *(const floatx4*)&pcG[w][lane][2][0];
                    floatx4 C = mf(a0, Bfwg[0], z4);
                    C = mf(a1, Bfwg[1], C);
                    float o0 = xr[0] * fsig(C[0]), o1 = xr[1] * fsig(C[1]);
                    float o2 = xr[2] * fsig(C[2]), o3 = xr[3] * fsig(C[3]);
                    st4c(&skx[m0 * 264 + 192 + nj], 264, o0, o1, o2, o3);
                }
                barx();                                    // C
                // ====== GRU finish + GLU x3 ======
#pragma unroll
                for (int G = 0; G < 3; ++G) {
                    {
                        const int inkb = (G == 0) ? 6 : (G == 1) ? 0 : 2;
                        floatx4 pr, pz, ph;
                        if (G == 0) { pr = pgr; pz = pgz; ph = pgh; }
                        else {
                            pr = *(const floatx4*)&pcG[w][lane][0][0];
                            pz = *(const floatx4*)&pcG[w][lane][1][0];
                            ph = *(const floatx4*)&pcG[w][lane][2][0];
                        }
                        short8 a0 = ldA(skx, 132, ln, inkb, lq);
                        short8 a1 = ldA(skx, 132, ln, inkb + 1, lq);
                        floatx4 Ci = mf(cps0, BiC[G][2], z4);
                        Ci = mf(cps1, BiC[G][3], Ci);
                        floatx4 Cr = mf(a0, BrC[G][0], z4);
                        floatx4 Cz = mf(a0, BzC[G][0], z4);
                        Ci = mf(a0, BiC[G][0], Ci);
                        Cr = mf(a1, BrC[G][1], Cr);
                        Cz = mf(a1, BzC[G][1], Cz);
                        Ci = mf(a1, BiC[G][1], Ci);
                        float sn[4];
#pragma unroll
                        for (int r = 0; r < 4; ++r) {
                            float rr = fsig(Cr[r] + pr[r]);
                            float zz = fsig(Cz[r] + pz[r]);
                            float nn = ftanh(Ci[r] + rr * ph[r]);
                            sn[r] = fmaf(zz, svr[G][r] - nn, nn);
                            svr[G][r] = sn[r];
                        }
                        st4c(&v64[m0 * 72 + nj], 72, sn[0], sn[1], sn[2], sn[3]);
                        if (G < 2)
                            st4c(&sgb[m0 * 72 + nj], 72,
                                 svr[G + 1][0], svr[G + 1][1], svr[G + 1][2], svr[G + 1][3]);
                    }
                    barx();                            // D/F/H
                    {
                        short8 a0 = ldA(v64, 36, ln, 0, lq);
                        short8 a1 = ldA(v64, 36, ln, 1, lq);
                        floatx4 C = mf(a0, Bg[G][0], z4);
                        C = mf(a1, Bg[G][1], C);
                        float o0 = svr[G][0] * fsig(C[0]), o1 = svr[G][1] * fsig(C[1]);
                        float o2 = svr[G][2] * fsig(C[2]), o3 = svr[G][3] * fsig(C[3]);
                        st4c(&skx[m0 * 264 + G * 64 + nj], 264, o0, o1, o2, o3);
                    }
                    barx();                            // E/G/I
                }
                // J: producer finishes SD
                barx();                                    // J
                // ====== K: SG (glu), both tiles ======
                {
                    short8 a0 = ldA(sdbb, 68, ln, 0, lq);
                    short8 a1 = ldA(sdbb, 68, ln, 1, lq);
                    short8 a2 = ldA(sdbb, 68, ln, 2, lq);
                    short8 a3 = ldA(sdbb, 68, ln, 3, lq);
                    floatx4 Ca = mf(a0, Bsg[0][0], z4), Cb = mf(a1, Bsg[0][1], z4);
                    floatx4 Cc = mf(a0, Bsg[1][0], z4), Cd = mf(a1, Bsg[1][1], z4);
                    Ca = mf(a2, Bsg[0][2], Ca); Cb = mf(a3, Bsg[0][3], Cb);
                    Cc = mf(a2, Bsg[1][2], Cc); Cd = mf(a3, Bsg[1][3], Cd);
                    float u0[4], u1[4];
#pragma unroll
                    for (int r = 0; r < 4; ++r) {
                        int m = m0 + r;
                        u0[r] = bf2f(sdbb[m * 136 + n0]) * fsig(Ca[r] + Cb[r]);
                        u1[r] = bf2f(sdbb[m * 136 + n1]) * fsig(Cc[r] + Cd[r]);
                    }
                    st4c(&sobb[m0 * 136 + n0], 136, u0[0], u0[1], u0[2], u0[3]);
                    st4c(&sobb[m0 * 136 + n1], 136, u1[0], u1[1], u1[2], u1[3]);
                }
                barx();                                    // K
                // ====== L: OUT (tanh) + state staging + global store ======
                {
                    short8 a0 = ldA(sobb, 68, ln, 0, lq);
                    short8 a1 = ldA(sobb, 68, ln, 1, lq);
                    short8 a2 = ldA(sobb, 68, ln, 2, lq);
                    short8 a3 = ldA(sobb, 68, ln, 3, lq);
                    floatx4 Ca = mf(a0, Bout[0], z4), Cb = mf(a1, Bout[1], z4);
                    Ca = mf(a2, Bout[2], Ca); Cb = mf(a3, Bout[3], Cb);
                    float ov[4];
#pragma unroll
                    for (int r = 0; r < 4; ++r) ov[r] = ftanh(Ca[r] + Cb[r]);
                    unsigned int q01 = cvtpk(ov[0], ov[1]), q23 = cvtpk(ov[2], ov[3]);
                    unsigned short ob[4] = {(unsigned short)q01, (unsigned short)(q01 >> 16),
                                            (unsigned short)q23, (unsigned short)(q23 >> 16)};
                    int hc = (base + nj) & 511;
#pragma unroll
                    for (int r = 0; r < 4; ++r) {
                        int m = m0 + r;
                        hist[m * HSTR + hc] = ob[r];
                        psb [m * 72 + nj]   = ob[r];
                        size_t oi = (size_t)(b0 + m) * (NFRAMES * NSUB * SS)
                                  + f * (NSUB * SS) + kk * SS + nj;
                        if (f32) ((float*)outp)[oi] = ov[r];
                        else     ((unsigned short*)outp)[oi] = ob[r];
                    }
                    st4c(&sgb[m0 * 72 + nj], 72, svr[0][0], svr[0][1], svr[0][2], svr[0][3]);
                }
                barx();                                    // L
                base += SS;
            }
        }
    } else {
        // ======================= PRODUCER (waves 4-7) =======================
        const int lane = t & 63, w4 = (t >> 6) - 4;
        const int lq = lane >> 4, ln = lane & 15;
        const int n0 = 32 * w4 + ln, n1 = n0 + 16;

        // resident B-frags: FW kb{0-5,9-12}; GRU r,z kb2-5; h; SD-ps weights
        short8 BfwP[10];
        short8 BrP[3][4], BzP[3][4], BhP[3][2];
        short8 BsdPS[2][2];
        const int fwkb[10] = {0, 1, 2, 3, 4, 5, 9, 10, 11, 12};
#pragma unroll
        for (int j = 0; j < 10; ++j)
            BfwP[j] = ldB(wbuf, OFF_FW + (w4 * 13 + fwkb[j]) * 64 + lane);
#pragma unroll
        for (int G = 0; G < 3; ++G) {
            const int OR = OFF_GRU(G), OZ = OR + 1536, OH = OR + 4096;
#pragma unroll
            for (int j = 0; j < 4; ++j) {
                BrP[G][j] = ldB(wbuf, OR + (w4 * 6 + 2 + j) * 64 + lane);
                BzP[G][j] = ldB(wbuf, OZ + (w4 * 6 + 2 + j) * 64 + lane);
            }
#pragma unroll
            for (int j = 0; j < 2; ++j)
                BhP[G][j] = ldB(wbuf, OH + (w4 * 2 + j) * 64 + lane);
        }
#pragma unroll
        for (int tl = 0; tl < 2; ++tl)
#pragma unroll
            for (int j = 0; j < 2; ++j)
                BsdPS[tl][j] = ldB(wbuf, OFF_SD + ((2 * w4 + tl) * 10 + 8 + j) * 64 + lane);

        int base = 0;
        for (int f = 0; f < NFRAMES; ++f) {
            for (int kk = 0; kk < NSUB; ++kk) {
                floatx4 SD00 = z4, SD01 = z4, SD10 = z4, SD11 = z4;
                short8 aps0, aps1, asg0, asg1;
                short8 W6[4], W0[4], W2[4], W4[4];

                // GRU partials (pure-reg): ps + s -> pcG
                auto grupart = [&](int G, short8 s0f, short8 s1f) {
                    floatx4 Cr = mf(aps0, BrP[G][0], z4);
                    floatx4 Cz = mf(aps0, BzP[G][0], z4);
                    Cr = mf(aps1, BrP[G][1], Cr);
                    Cz = mf(aps1, BzP[G][1], Cz);
                    floatx4 Ch = mf(s0f, BhP[G][0], z4);
                    Cr = mf(s0f, BrP[G][2], Cr);
                    Cz = mf(s0f, BzP[G][2], Cz);
                    Ch = mf(s1f, BhP[G][1], Ch);
                    Cr = mf(s1f, BrP[G][3], Cr);
                    Cz = mf(s1f, BzP[G][3], Cz);
                    *(floatx4*)&pcG[w4][lane][0][0] = Cr;
                    *(floatx4*)&pcG[w4][lane][1][0] = Cz;
                    *(floatx4*)&pcG[w4][lane][2][0] = Ch;
                };
                // SD 2-kb segment, weights in regs
                auto sdsegW = [&](int kbs, short8* W) {
                    short8 a0 = ldA(skx, 132, ln, kbs, lq);
                    short8 a1 = ldA(skx, 132, ln, kbs + 1, lq);
                    SD00 = mf(a0, W[0], SD00); SD10 = mf(a0, W[1], SD10);
                    SD01 = mf(a1, W[2], SD01); SD11 = mf(a1, W[3], SD11);
                };
                auto ldW = [&](int kb, short8* W) {
                    W[0] = ldA(wsd, 164, n0, kb, lq);
                    W[1] = ldA(wsd, 164, n1, kb, lq);
                    W[2] = ldA(wsd, 164, n0, kb + 1, lq);
                    W[3] = ldA(wsd, 164, n1, kb + 1, lq);
                };

                // ====== A: gather + ps/s loads + FW partials + SD-ps ======
                {
                    int per = period_s[prow];
#pragma unroll
                    for (int ii = 0; ii < 5; ++ii) {
                        int i = px16 * 5 + ii;
                        if (i < 68) {
                            int idx = LPREV - per + i - 2;
                            if (idx >= LPREV) idx -= per;
                            catb[prow * 424 + 192 + i] = hist[prow * HSTR + ((base + idx) & 511)];
                        }
                    }
                    aps0 = ldA(psb, 36, ln, 0, lq);
                    aps1 = ldA(psb, 36, ln, 1, lq);
                    asg0 = ldA(sgb, 36, ln, 0, lq);
                    asg1 = ldA(sgb, 36, ln, 1, lq);
                    short8 c0 = ldA(catb, 212, ln, 0, lq);
                    short8 c1 = ldA(catb, 212, ln, 1, lq);
                    short8 c2 = ldA(catb, 212, ln, 2, lq);
                    short8 c3 = ldA(catb, 212, ln, 3, lq);
                    short8 c9 = ldA(catb, 212, ln, 9, lq);
                    short8 cA = ldA(catb, 212, ln, 10, lq);
                    short8 cB = ldA(catb, 212, ln, 11, lq);
                    short8 cC = ldA(catb, 212, ln, 12, lq);
                    floatx4 C0 = mf(c0, BfwP[0], z4);
                    floatx4 C1 = mf(c1, BfwP[1], z4);
                    floatx4 C2 = mf(c2, BfwP[2], z4);
                    floatx4 C3 = mf(c3, BfwP[3], z4);
                    C0 = mf(aps0, BfwP[4], C0);
                    C1 = mf(aps1, BfwP[5], C1);
                    C2 = mf(c9, BfwP[6], C2);
                    C3 = mf(cA, BfwP[7], C3);
                    C0 = mf(cB, BfwP[8], C0);
                    C1 = mf(cC, BfwP[9], C1);
                    // SD ps segment (kb8,9), weights resident
                    SD00 = mf(aps0, BsdPS[0][0], SD00);
                    SD10 = mf(aps0, BsdPS[1][0], SD10);
                    SD01 = mf(aps1, BsdPS[0][1], SD01);
                    SD11 = mf(aps1, BsdPS[1][1], SD11);
                    floatx4 s = (C0 + C1) + (C2 + C3);
                    *(floatx4*)&pcFW[w4][lane][0] = s;
                }
                barx();                                    // A
                // ====== B: GRU1 partials (pure reg) ======
                grupart(0, asg0, asg1);
                barx();                                    // B
                // ====== C: prefetch wsd fw-segment weights ======
                ldW(6, W6);
                barx();                                    // C
                // ====== D: SD fw (kb6,7); prefetch o1 weights ======
                sdsegW(6, W6);
                ldW(0, W0);
                barx();                                    // D
                // ====== E: GRU2 partials ======
                {
                    short8 s0f = ldA(sgb, 36, ln, 0, lq);
                    short8 s1f = ldA(sgb, 36, ln, 1, lq);
                    grupart(1, s0f, s1f);
                }
                barx();                                    // E
                // ====== F: SD o1 (kb0,1); prefetch o2 weights ======
                sdsegW(0, W0);
                ldW(2, W2);
                barx();                                    // F
                // ====== G: GRU3 partials ======
                {
                    short8 s0f = ldA(sgb, 36, ln, 0, lq);
                    short8 s1f = ldA(sgb, 36, ln, 1, lq);
                    grupart(2, s0f, s1f);
                }
                barx();                                    // G
                // ====== H: SD o2 (kb2,3); prefetch o3 weights ======
                sdsegW(2, W2);
                ldW(4, W4);
                barx();                                    // H
                // ====== I: idle ======
                barx();                                    // I
                // ====== J: SD o3 (kb4,5) + tanh -> sdbb ======
                {
                    sdsegW(4, W4);
                    float t0[4], t1[4];
#pragma unroll
                    for (int r = 0; r < 4; ++r) {
                        t0[r] = ftanh(SD00[r] + SD01[r]);
                        t1[r] = ftanh(SD10[r] + SD11[r]);
                    }
                    st4c(&sdbb[(4 * lq) * 136 + n0], 136, t0[0], t0[1], t0[2], t0[3]);
                    st4c(&sdbb[(4 * lq) * 136 + n1], 136, t1[0], t1[1], t1[2], t1[3]);
                }
                barx();                                    // J
                // ====== K: idle ======
                barx();                                    // K
                // ====== L: feat2s shuffle + prefetch + period ======
                {
                    unsigned int* cat32 = (unsigned int*)catb;
                    int cb = prow * 212;
                    int u0 = pe8 >> 1;
                    unsigned int o0 = cat32[cb + u0 + 0];
                    unsigned int o1 = cat32[cb + u0 + 1];
                    unsigned int o2 = cat32[cb + u0 + 2];
                    unsigned int o3 = cat32[cb + u0 + 3];
                    cat32[cb + 130 + u0 + 0] = o0;
                    cat32[cb + 130 + u0 + 1] = o1;
                    cat32[cb + 130 + u0 + 2] = o2;
                    cat32[cb + 130 + u0 + 3] = o3;
                    *(uint4*)(cat32 + cb + u0) = pfc;
                    int sN = f * 4 + kk + 2;
                    if (sN > NFRAMES * 4 - 1) sN = NFRAMES * 4 - 1;
                    pfc = *(const uint4*)(cb16
                        + ((size_t)(b0 + prow) * NFRAMES + (sN >> 2)) * 512 + (sN & 3) * 128 + pe8);
                    if (kk == 0 && t < 256 + RPW) {
                        int fN = (f + 1 < NFRAMES) ? f + 1 : f;
                        pper = ld1f(f32, feats,
                                    (size_t)(b0 + (t - 256)) * (NF * NFRAMES) + (NF - 1) * NFRAMES + fN);
                    }
                    if (kk == 3 && t < 256 + RPW) period_s[t - 256] = (int)rintf(pper);
                }
                barx();                                    // L
                base += SS;
            }
        }
    }
}

// ---------- launch ----------
extern "C" void kernel_launch(void* const* d_in, const int* in_sizes, int n_in,
                              void* d_out, int out_size, void* d_ws, size_t ws_size,
                              hipStream_t stream) {
    const void* feats = d_in[0];
    const void* gfeat = d_in[1];
    const void* prev  = d_in[2];
    const void* Wc1   = d_in[3];
    const void* Wc2   = d_in[4];
    const void* Wc3   = d_in[5];
    const void* Wfw   = d_in[6];
    const void* Wfwg  = d_in[7];
    const void* Wih1  = d_in[8];
    const void* Whh1  = d_in[9];
    const void* Wih2  = d_in[10];
    const void* Whh2  = d_in[11];
    const void* Wih3  = d_in[12];
    const void* Whh3  = d_in[13];
    const void* Wg1   = d_in[14];
    const void* Wg2   = d_in[15];
    const void* Wg3   = d_in[16];
    const void* Wsg   = d_in[17];
    const void* Wsd   = d_in[18];
    const void* Wout  = d_in[19];

    int*            flag = (int*)d_ws;                                      // @0
    unsigned short* cb16 = (unsigned short*)((char*)d_ws + 256);            // 6,553,600 B
    unsigned int*   wct  = (unsigned int*)((char*)d_ws + 256 + 6553600);    // 524,288 B
    uint4*          wbuf = (uint4*)((char*)d_ws + 256 + 6553600 + 524288);  // 438,272 B

    fargan_detect<<<1, 1, 0, stream>>>(feats, flag);
    fargan_prep<<<(NFRAG + 255) / 256, 256, 0, stream>>>(flag, Wfw, Wfwg,
        Wih1, Whh1, Wih2, Whh2, Wih3, Whh3, Wg1, Wg2, Wg3, Wsg, Wsd, Wout, wbuf);
    fargan_prep_conv<<<512, 256, 0, stream>>>(flag, Wc1, Wc2, Wc3, wct);
    fargan_conv<<<BATCH * 25, 256, 0, stream>>>(feats, gfeat, flag, wct, cb16);
    fargan_seq<<<BATCH / RPW, 512, 0, stream>>>(feats, prev, flag, cb16, wbuf, d_out);
}